// Round 13
// baseline (936.907 us; speedup 1.0000x reference)
//
#include <hip/hip_runtime.h>
#include <math.h>

#define T_LEN 8192
#define HID   2048
#define NHEAD 16
#define HD    128
#define NBLK  512
#define NIDX  196                    // 64+64+64+4 used index-path columns
#define SCALE 0.08838834764831845f   // 1/sqrt(128)

typedef unsigned short u16;
typedef unsigned short u16x8 __attribute__((ext_vector_type(8)));
typedef float f32x4 __attribute__((ext_vector_type(4)));

// ---- bf16 <-> f32 via bit ops (RNE) ----
__device__ __forceinline__ u16 f2b(float f) {
  unsigned int u = __float_as_uint(f);
  return (u16)((u + 0x7fffu + ((u >> 16) & 1u)) >> 16);
}
__device__ __forceinline__ float b2f(u16 s) {
  return __uint_as_float(((unsigned int)s) << 16);
}

// ---- async global->LDS, 16B per lane (dest must be wave-linear) ----
__device__ __forceinline__ void gload16(const u16* g, u16* l) {
  __builtin_amdgcn_global_load_lds(
      (__attribute__((address_space(1))) void*)(uintptr_t)g,
      (__attribute__((address_space(3))) void*)(unsigned int)(uintptr_t)l,
      16, 0, 0);
}

// ---- MFMA 16x16x32 bf16 via inline asm (D/C tied) ----
__device__ __forceinline__ void mfma16(f32x4& d, u16x8 a, u16x8 b) {
  asm("v_mfma_f32_16x16x32_bf16 %0, %1, %2, %0" : "+v"(d) : "v"(a), "v"(b));
}

// ---------------------------------------------------------------------------
// bf16 MFMA GEMM: C[M,N] = A[M,K] @ Bt[N,K]^T.  m97 structure, 128x128 tile.
// ---------------------------------------------------------------------------
template<int OUT_BF16>
__global__ __launch_bounds__(256) void bgemm_k(
    const u16* __restrict__ A, int lda,
    const u16* __restrict__ Bt, int ldb,
    void* __restrict__ Cp, int ldc, int K)
{
  __shared__ __align__(16) u16 Al[128 * 32];
  __shared__ __align__(16) u16 Bl[128 * 32];
  const int tid = threadIdx.x;
  const int lane = tid & 63;
  const int bm = blockIdx.y * 128;
  const int bn = blockIdx.x * 128;
  const int wr = ((tid >> 6) >> 1) * 64;
  const int wc = ((tid >> 6) & 1) * 64;
  const int r0 = tid >> 2;
  const int c0 = (tid & 3) * 8;
  const u16* ga0 = A  + (size_t)(bm + r0) * lda + c0;
  const u16* ga1 = ga0 + (size_t)64 * lda;
  const u16* gb0 = Bt + (size_t)(bn + r0) * ldb + c0;
  const u16* gb1 = gb0 + (size_t)64 * ldb;
  u16* la0 = Al + tid * 8;
  u16* la1 = Al + (tid + 256) * 8;
  u16* lb0 = Bl + tid * 8;
  u16* lb1 = Bl + (tid + 256) * 8;

  f32x4 zero = {0.f, 0.f, 0.f, 0.f};
  f32x4 acc[4][4];
  #pragma unroll
  for (int m = 0; m < 4; ++m)
    #pragma unroll
    for (int n = 0; n < 4; ++n) acc[m][n] = zero;

  const int ar = wr + (lane & 15);
  const int br = wc + (lane & 15);
  const int ko = (lane >> 4) * 8;

  for (int k0 = 0; k0 < K; k0 += 32) {
    gload16(ga0 + k0, la0);
    gload16(ga1 + k0, la1);
    gload16(gb0 + k0, lb0);
    gload16(gb1 + k0, lb1);
    __syncthreads();
    u16x8 af[4], bfr[4];
    #pragma unroll
    for (int m = 0; m < 4; ++m)
      af[m] = *(const u16x8*)(Al + (size_t)(ar + m * 16) * 32 + ko);
    #pragma unroll
    for (int n = 0; n < 4; ++n)
      bfr[n] = *(const u16x8*)(Bl + (size_t)(br + n * 16) * 32 + ko);
    #pragma unroll
    for (int m = 0; m < 4; ++m)
      #pragma unroll
      for (int n = 0; n < 4; ++n) mfma16(acc[m][n], af[m], bfr[n]);
    __syncthreads();
  }
  asm volatile("s_nop 7\n\ts_nop 7");
  const int er = (lane >> 4) * 4;
  const int ec = lane & 15;
  #pragma unroll
  for (int m = 0; m < 4; ++m)
    #pragma unroll
    for (int n = 0; n < 4; ++n)
      #pragma unroll
      for (int r = 0; r < 4; ++r) {
        size_t idx = (size_t)(bm + wr + m * 16 + er + r) * ldc + (bn + wc + n * 16 + ec);
        if (OUT_BF16) ((u16*)Cp)[idx] = f2b(acc[m][n][r]);
        else          ((float*)Cp)[idx] = acc[m][n][r];
      }
}

// ---------------------------------------------------------------------------
// Fused qc|kv projection GEMM: A = hb (8192x2048), Bt = [w_qcT(512) ; kvT(512)]
// (1024x2048).  Cols 0-511 -> Cq bf16 (ld 512); cols 512-1023 -> Ckv f32 (ld 512).
// ---------------------------------------------------------------------------
__global__ __launch_bounds__(256) void bgemm_qckv_k(
    const u16* __restrict__ A, const u16* __restrict__ Bt,
    u16* __restrict__ Cq, float* __restrict__ Ckv)
{
  __shared__ __align__(16) u16 Al[128 * 32];
  __shared__ __align__(16) u16 Bl[128 * 32];
  const int tid = threadIdx.x;
  const int lane = tid & 63;
  const int bm = blockIdx.y * 128;
  const int bn = blockIdx.x * 128;
  const int wr = ((tid >> 6) >> 1) * 64;
  const int wc = ((tid >> 6) & 1) * 64;
  const int r0 = tid >> 2;
  const int c0 = (tid & 3) * 8;
  const u16* ga0 = A  + (size_t)(bm + r0) * 2048 + c0;
  const u16* ga1 = ga0 + (size_t)64 * 2048;
  const u16* gb0 = Bt + (size_t)(bn + r0) * 2048 + c0;
  const u16* gb1 = gb0 + (size_t)64 * 2048;
  u16* la0 = Al + tid * 8;
  u16* la1 = Al + (tid + 256) * 8;
  u16* lb0 = Bl + tid * 8;
  u16* lb1 = Bl + (tid + 256) * 8;

  f32x4 zero = {0.f, 0.f, 0.f, 0.f};
  f32x4 acc[4][4];
  #pragma unroll
  for (int m = 0; m < 4; ++m)
    #pragma unroll
    for (int n = 0; n < 4; ++n) acc[m][n] = zero;

  const int ar = wr + (lane & 15);
  const int br = wc + (lane & 15);
  const int ko = (lane >> 4) * 8;

  for (int k0 = 0; k0 < 2048; k0 += 32) {
    gload16(ga0 + k0, la0);
    gload16(ga1 + k0, la1);
    gload16(gb0 + k0, lb0);
    gload16(gb1 + k0, lb1);
    __syncthreads();
    u16x8 af[4], bfr[4];
    #pragma unroll
    for (int m = 0; m < 4; ++m)
      af[m] = *(const u16x8*)(Al + (size_t)(ar + m * 16) * 32 + ko);
    #pragma unroll
    for (int n = 0; n < 4; ++n)
      bfr[n] = *(const u16x8*)(Bl + (size_t)(br + n * 16) * 32 + ko);
    #pragma unroll
    for (int m = 0; m < 4; ++m)
      #pragma unroll
      for (int n = 0; n < 4; ++n) mfma16(acc[m][n], af[m], bfr[n]);
    __syncthreads();
  }
  asm volatile("s_nop 7\n\ts_nop 7");
  const int er = (lane >> 4) * 4;
  const int ec = lane & 15;
  if (bn < 512) {
    #pragma unroll
    for (int m = 0; m < 4; ++m)
      #pragma unroll
      for (int n = 0; n < 4; ++n)
        #pragma unroll
        for (int r = 0; r < 4; ++r)
          Cq[(size_t)(bm + wr + m * 16 + er + r) * 512 + (bn + wc + n * 16 + ec)]
              = f2b(acc[m][n][r]);
  } else {
    #pragma unroll
    for (int m = 0; m < 4; ++m)
      #pragma unroll
      for (int n = 0; n < 4; ++n)
        #pragma unroll
        for (int r = 0; r < 4; ++r)
          Ckv[(size_t)(bm + wr + m * 16 + er + r) * 512 + (bn - 512 + wc + n * 16 + ec)]
              = acc[m][n][r];
  }
}

// ---------------------------------------------------------------------------
// Fused group projection: z = group.  A = attnb + z*512 (ld 2048), K=512,
// Bt = gwT + z*512*512, C = og + z*512 (ld 2048) bf16.
// ---------------------------------------------------------------------------
__global__ __launch_bounds__(256) void bgemm_group_k(
    const u16* __restrict__ Ab, const u16* __restrict__ gw,
    u16* __restrict__ Cb)
{
  __shared__ __align__(16) u16 Al[128 * 32];
  __shared__ __align__(16) u16 Bl[128 * 32];
  const int tid = threadIdx.x;
  const int lane = tid & 63;
  const int bm = blockIdx.y * 128;
  const int bn = blockIdx.x * 128;
  const int g  = blockIdx.z;
  const u16* A  = Ab + (size_t)g * 512;
  const u16* Bt = gw + (size_t)g * 512 * 512;
  u16* C = Cb + (size_t)g * 512;
  const int wr = ((tid >> 6) >> 1) * 64;
  const int wc = ((tid >> 6) & 1) * 64;
  const int r0 = tid >> 2;
  const int c0 = (tid & 3) * 8;
  const u16* ga0 = A  + (size_t)(bm + r0) * 2048 + c0;
  const u16* ga1 = ga0 + (size_t)64 * 2048;
  const u16* gb0 = Bt + (size_t)(bn + r0) * 512 + c0;
  const u16* gb1 = gb0 + (size_t)64 * 512;
  u16* la0 = Al + tid * 8;
  u16* la1 = Al + (tid + 256) * 8;
  u16* lb0 = Bl + tid * 8;
  u16* lb1 = Bl + (tid + 256) * 8;

  f32x4 zero = {0.f, 0.f, 0.f, 0.f};
  f32x4 acc[4][4];
  #pragma unroll
  for (int m = 0; m < 4; ++m)
    #pragma unroll
    for (int n = 0; n < 4; ++n) acc[m][n] = zero;

  const int ar = wr + (lane & 15);
  const int br = wc + (lane & 15);
  const int ko = (lane >> 4) * 8;

  for (int k0 = 0; k0 < 512; k0 += 32) {
    gload16(ga0 + k0, la0);
    gload16(ga1 + k0, la1);
    gload16(gb0 + k0, lb0);
    gload16(gb1 + k0, lb1);
    __syncthreads();
    u16x8 af[4], bfr[4];
    #pragma unroll
    for (int m = 0; m < 4; ++m)
      af[m] = *(const u16x8*)(Al + (size_t)(ar + m * 16) * 32 + ko);
    #pragma unroll
    for (int n = 0; n < 4; ++n)
      bfr[n] = *(const u16x8*)(Bl + (size_t)(br + n * 16) * 32 + ko);
    #pragma unroll
    for (int m = 0; m < 4; ++m)
      #pragma unroll
      for (int n = 0; n < 4; ++n) mfma16(acc[m][n], af[m], bfr[n]);
    __syncthreads();
  }
  asm volatile("s_nop 7\n\ts_nop 7");
  const int er = (lane >> 4) * 4;
  const int ec = lane & 15;
  #pragma unroll
  for (int m = 0; m < 4; ++m)
    #pragma unroll
    for (int n = 0; n < 4; ++n)
      #pragma unroll
      for (int r = 0; r < 4; ++r)
        C[(size_t)(bm + wr + m * 16 + er + r) * 2048 + (bn + wc + n * 16 + ec)]
            = f2b(acc[m][n][r]);
}

// ---------------------------------------------------------------------------
// f32 GEMM with split-K, 128x64 tile, 8x4 micro-tile.  Per-output-element
// K-summation order identical to the 64x64 version (k0 asc, kk asc) ->
// bit-identical results.  blockIdx.z selects K-chunk; partials P[z][M][ldc].
// ---------------------------------------------------------------------------
__global__ __launch_bounds__(256) void sgemm_splitk_k(
    const float* __restrict__ A, int lda,
    const float* __restrict__ B, int ldb,
    float* __restrict__ P, int ldc,
    int M, int N, int kchunk)
{
  __shared__ __align__(16) float As[16][132];   // [BK][BM=128 +4 pad]
  __shared__ __align__(16) float Bs[16][68];    // [BK][BN=64 +4 pad]
  const int bm = blockIdx.y * 128;
  const int bn = blockIdx.x * 64;
  const int kb = blockIdx.z * kchunk;
  float* C = P + (size_t)blockIdx.z * M * ldc;
  const int tid = threadIdx.x;
  const int tx = tid & 15;       // col group (4 cols)
  const int ty = tid >> 4;       // row group (8 rows)
  float acc[8][4] = {};
  for (int k0 = 0; k0 < kchunk; k0 += 16) {
    #pragma unroll
    for (int i = 0; i < 8; ++i) {
      int f = tid + i * 256;           // 0..2047 -> A tile 128x16
      int r = f >> 4, c = f & 15;
      As[c][r] = A[(size_t)(bm + r) * lda + (kb + k0 + c)];
    }
    #pragma unroll
    for (int i = 0; i < 4; ++i) {
      int f = tid + i * 256;           // 0..1023 -> B tile 16x64
      int r = f >> 6, c = f & 63;
      float v = 0.f;
      int gc = bn + c;
      if (gc < N) v = B[(size_t)(kb + k0 + r) * ldb + gc];
      Bs[r][c] = v;
    }
    __syncthreads();
    #pragma unroll
    for (int kk = 0; kk < 16; ++kk) {
      float4 a0 = *(const float4*)&As[kk][ty * 8];
      float4 a1 = *(const float4*)&As[kk][ty * 8 + 4];
      float4 b  = *(const float4*)&Bs[kk][tx * 4];
      float av[8] = {a0.x, a0.y, a0.z, a0.w, a1.x, a1.y, a1.z, a1.w};
      float bv[4] = {b.x, b.y, b.z, b.w};
      #pragma unroll
      for (int i = 0; i < 8; ++i)
        #pragma unroll
        for (int j = 0; j < 4; ++j) acc[i][j] += av[i] * bv[j];
    }
    __syncthreads();
  }
  #pragma unroll
  for (int i = 0; i < 8; ++i) {
    int gr = bm + ty * 8 + i;
    #pragma unroll
    for (int j = 0; j < 4; ++j) {
      int gc = bn + tx * 4 + j;
      if (gc < N) C[(size_t)gr * ldc + gc] = acc[i][j];
    }
  }
}

// ---- sum 4 split-K partials [4][M][ldp] -> out[M][ldo] ----
__global__ void reduce4_k(const float* __restrict__ P, int ldp,
                          float* __restrict__ o, int ldo, int M)
{
  int i = blockIdx.x * 256 + threadIdx.x;
  if (i >= M * ldp) return;
  int r = i / ldp, c = i % ldp;
  size_t st = (size_t)M * ldp;
  float v = P[i] + P[i + st] + P[i + 2 * st] + P[i + 3 * st];
  o[(size_t)r * ldo + c] = v;
}

// ---------------------------------------------------------------------------
// Generic tiled f32 GEMM (small-K qib GEMM), vectorized LDS reads.
// ---------------------------------------------------------------------------
__global__ __launch_bounds__(256) void sgemm_k(
    const float* __restrict__ A, int lda,
    const float* __restrict__ B, int ldb,
    float* __restrict__ C, int ldc,
    int M, int N, int K)
{
  __shared__ __align__(16) float As[16][68];
  __shared__ __align__(16) float Bs[16][68];
  const int bm = blockIdx.y * 64;
  const int bn = blockIdx.x * 64;
  const int tid = threadIdx.x;
  const int tx = tid & 15;
  const int ty = tid >> 4;
  float acc[4][4] = {};
  for (int k0 = 0; k0 < K; k0 += 16) {
    #pragma unroll
    for (int i = 0; i < 4; ++i) {
      int f = tid + i * 256;
      int r = f >> 4, c = f & 15;
      float v = 0.f;
      int gr = bm + r, gc = k0 + c;
      if (gr < M && gc < K) v = A[(size_t)gr * lda + gc];
      As[c][r] = v;
    }
    #pragma unroll
    for (int i = 0; i < 4; ++i) {
      int f = tid + i * 256;
      int r = f >> 6, c = f & 63;
      float v = 0.f;
      int gr = k0 + r, gc = bn + c;
      if (gr < K && gc < N) v = B[(size_t)gr * ldb + gc];
      Bs[r][c] = v;
    }
    __syncthreads();
    #pragma unroll
    for (int kk = 0; kk < 16; ++kk) {
      float4 a = *(const float4*)&As[kk][ty * 4];
      float4 b = *(const float4*)&Bs[kk][tx * 4];
      float av[4] = {a.x, a.y, a.z, a.w};
      float bv[4] = {b.x, b.y, b.z, b.w};
      #pragma unroll
      for (int i = 0; i < 4; ++i)
        #pragma unroll
        for (int j = 0; j < 4; ++j) acc[i][j] += av[i] * bv[j];
    }
    __syncthreads();
  }
  #pragma unroll
  for (int i = 0; i < 4; ++i) {
    int gr = bm + ty * 4 + i;
    if (gr >= M) continue;
    #pragma unroll
    for (int j = 0; j < 4; ++j) {
      int gc = bn + tx * 4 + j;
      if (gc < N) C[(size_t)gr * ldc + gc] = acc[i][j];
    }
  }
}

// ---------------------------------------------------------------------------
// f32 -> bf16 cast (4 elems/thread)
// ---------------------------------------------------------------------------
__global__ void castk(const float* __restrict__ in, u16* __restrict__ out, int n4)
{
  int i = blockIdx.x * 256 + threadIdx.x;
  if (i >= n4) return;
  float4 v = ((const float4*)in)[i];
  unsigned int lo = (unsigned int)f2b(v.x) | ((unsigned int)f2b(v.y) << 16);
  unsigned int hi = (unsigned int)f2b(v.z) | ((unsigned int)f2b(v.w) << 16);
  ((uint2*)out)[i] = make_uint2(lo, hi);
}

// ---------------------------------------------------------------------------
// transpose + cast: in f32 [R][C] -> out bf16 [C][R]
// ---------------------------------------------------------------------------
__global__ __launch_bounds__(256) void tcast_k(
    const float* __restrict__ in, u16* __restrict__ outT, int R, int C)
{
  __shared__ float t[32][33];
  int bc = blockIdx.x * 32, br = blockIdx.y * 32;
  int lx = threadIdx.x & 31, ly = threadIdx.x >> 5;
  #pragma unroll
  for (int i = 0; i < 32; i += 8) {
    int r = br + ly + i, c = bc + lx;
    t[ly + i][lx] = (r < R && c < C) ? in[(size_t)r * C + c] : 0.f;
  }
  __syncthreads();
  #pragma unroll
  for (int i = 0; i < 32; i += 8) {
    int c = bc + ly + i, r = br + lx;
    if (c < C && r < R) outT[(size_t)c * R + r] = f2b(t[lx][ly + i]);
  }
}

// ---------------------------------------------------------------------------
// Concat the 4 index-path weights into Bcat f32 (2048 x 196)
// ---------------------------------------------------------------------------
__global__ void concat_idx_k(const float* __restrict__ a, const float* __restrict__ b,
                             const float* __restrict__ c, const float* __restrict__ d,
                             float* __restrict__ o)
{
  int i = blockIdx.x * 256 + threadIdx.x;
  if (i >= 2048 * NIDX) return;
  int r = i / NIDX, col = i % NIDX;
  float v = (col < 64)  ? a[r * 64 + col]
          : (col < 128) ? b[r * 64 + col - 64]
          : (col < 192) ? c[r * 64 + col - 128]
          :               d[r * 4 + col - 192];
  o[i] = v;
}

// ---------------------------------------------------------------------------
// RoPE cos/sin tables: (T, 32) each.
// ---------------------------------------------------------------------------
__global__ void rope_cs_k(float* __restrict__ ct, float* __restrict__ st)
{
  int idx = blockIdx.x * blockDim.x + threadIdx.x;
  if (idx >= T_LEN * 32) return;
  int t = idx >> 5, i = idx & 31;
  float inv = powf(10000.0f, -(float)(2 * i) / 64.0f);
  float ang = (float)t * inv;
  ct[idx] = cosf(ang);
  st[idx] = sinf(ang);
}

// ---------------------------------------------------------------------------
// q (bf16, row = t*16+h): rope then rmsnorm, in place. 4 rows/block (1/wave).
// ---------------------------------------------------------------------------
__global__ __launch_bounds__(256) void q_rope_norm_k(
    u16* __restrict__ q, const float* __restrict__ ct,
    const float* __restrict__ st, const float* __restrict__ w)
{
  int wid = threadIdx.x >> 6;
  int row = blockIdx.x * 4 + wid;
  int t = row >> 4;
  int lane = threadIdx.x & 63;
  __shared__ float ls[4][128];
  u16* rp = q + (size_t)row * 128;
  ls[wid][lane] = b2f(rp[lane]);
  ls[wid][lane + 64] = b2f(rp[lane + 64]);
  __syncthreads();
  float v0;
  if (lane < 32) {
    float c = ct[t * 32 + lane], s = st[t * 32 + lane];
    v0 = ls[wid][lane] * c - ls[wid][lane + 32] * s;
  } else {
    int i = lane - 32;
    float c = ct[t * 32 + i], s = st[t * 32 + i];
    v0 = ls[wid][i] * s + ls[wid][lane] * c;
  }
  float v1 = ls[wid][lane + 64];
  float ss = v0 * v0 + v1 * v1;
  #pragma unroll
  for (int off = 1; off < 64; off <<= 1) ss += __shfl_xor(ss, off);
  float rn = 1.0f / sqrtf(ss / 128.0f + 1e-6f);
  rp[lane] = f2b(v0 * rn * w[lane]);
  rp[lane + 64] = f2b(v1 * rn * w[lane + 64]);
}

// ---------------------------------------------------------------------------
// sw_k inside kvout (f32, row stride 512, cols 0..127): rmsnorm then rope.
// ---------------------------------------------------------------------------
__global__ __launch_bounds__(256) void k_norm_rope_k(
    float* __restrict__ kv, const float* __restrict__ ct,
    const float* __restrict__ st, const float* __restrict__ w)
{
  int wid = threadIdx.x >> 6;
  int t = blockIdx.x * 4 + wid;
  int lane = threadIdx.x & 63;
  __shared__ float ls[4][128];
  float* rp = kv + (size_t)t * 512;
  float a = rp[lane], b = rp[lane + 64];
  float ss = a * a + b * b;
  #pragma unroll
  for (int off = 1; off < 64; off <<= 1) ss += __shfl_xor(ss, off);
  float rn = 1.0f / sqrtf(ss / 128.0f + 1e-6f);
  a *= rn * w[lane];
  b *= rn * w[lane + 64];
  ls[wid][lane] = a;
  ls[wid][lane + 64] = b;
  __syncthreads();
  float v0;
  if (lane < 32) {
    float c = ct[t * 32 + lane], s = st[t * 32 + lane];
    v0 = ls[wid][lane] * c - ls[wid][lane + 32] * s;
  } else {
    int i = lane - 32;
    float c = ct[t * 32 + i], s = st[t * 32 + i];
    v0 = ls[wid][i] * s + ls[wid][lane] * c;
  }
  rp[lane] = v0;
  rp[lane + 64] = b;
}

// ---------------------------------------------------------------------------
// rmsnorm 128-wide f32 rows in place.  4 rows per block (1/wave).
// ---------------------------------------------------------------------------
__global__ __launch_bounds__(256) void rms_rows_k(
    float* __restrict__ x, const float* __restrict__ w)
{
  int r = blockIdx.x * 4 + (threadIdx.x >> 6);
  int lane = threadIdx.x & 63;
  float* rp = x + (size_t)r * 128;
  float a = rp[lane], b = rp[lane + 64];
  float ss = a * a + b * b;
  #pragma unroll
  for (int off = 1; off < 64; off <<= 1) ss += __shfl_xor(ss, off);
  float rn = 1.0f / sqrtf(ss / 128.0f + 1e-6f);
  rp[lane] = a * rn * w[lane];
  rp[lane + 64] = b * rn * w[lane + 64];
}

// ---------------------------------------------------------------------------
// compress with input row-stride ldin: out[n*sn + d*sd]
// ---------------------------------------------------------------------------
__global__ void compress_k(
    const float* __restrict__ c, const float* __restrict__ z, int ldin,
    const float* __restrict__ bias, float* __restrict__ out,
    int D, int sn, int sd)
{
  int idx = blockIdx.x * blockDim.x + threadIdx.x;
  if (idx >= NBLK * D) return;
  int n = idx / D, d = idx % D;
  float zb[16];
  float mx = -INFINITY;
  #pragma unroll
  for (int m = 0; m < 16; ++m) {
    float v = z[(size_t)(n * 16 + m) * ldin + d] + bias[m * D + d];
    zb[m] = v;
    mx = fmaxf(mx, v);
  }
  float s = 0.f;
  #pragma unroll
  for (int m = 0; m < 16; ++m) { zb[m] = expf(zb[m] - mx); s += zb[m]; }
  float acc = 0.f;
  #pragma unroll
  for (int m = 0; m < 16; ++m) acc += zb[m] * c[(size_t)(n * 16 + m) * ldin + d];
  out[(size_t)n * sn + (size_t)d * sd] = acc / s;
}

// ---------------------------------------------------------------------------
// Top-64 per t, fully in-register, one wave per t (4 waves/block).
// ---------------------------------------------------------------------------
__global__ __launch_bounds__(256) void topk_k(
    const float* __restrict__ qi,    // (T, 4, 64)
    const float* __restrict__ wih, int wst,
    const float* __restrict__ kT,    // (64, 512)
    int* __restrict__ top_idx)       // (T, 64)
{
  const int wid = threadIdx.x >> 6;
  const int lane = threadIdx.x & 63;
  const int t = blockIdx.x * 4 + wid;
  __shared__ float qs[4][256];
  for (int i = lane; i < 256; i += 64) qs[wid][i] = qi[(size_t)t * 256 + i];
  float wh[4];
  #pragma unroll
  for (int h = 0; h < 4; ++h) wh[h] = wih[(size_t)t * wst + h];
  __syncthreads();

  float d[4][8] = {};
  for (int cc = 0; cc < 64; ++cc) {
    const float4* kp = (const float4*)(kT + (size_t)cc * 512 + lane * 8);
    float4 k0 = kp[0], k1 = kp[1];
    float kv[8] = {k0.x, k0.y, k0.z, k0.w, k1.x, k1.y, k1.z, k1.w};
    #pragma unroll
    for (int h = 0; h < 4; ++h) {
      float qv = qs[wid][h * 64 + cc];
      #pragma unroll
      for (int s = 0; s < 8; ++s) d[h][s] += qv * kv[s];
    }
  }
  float sc[8];
  #pragma unroll
  for (int s = 0; s < 8; ++s) {
    int n = lane * 8 + s;
    float v = wh[0] * fmaxf(d[0][s], 0.f) + wh[1] * fmaxf(d[1][s], 0.f)
            + wh[2] * fmaxf(d[2][s], 0.f) + wh[3] * fmaxf(d[3][s], 0.f);
    sc[s] = (n * 16 + 15 < t) ? v : -INFINITY;
  }
  float bv = -INFINITY; int bs = 0;
  #pragma unroll
  for (int s = 0; s < 8; ++s) if (sc[s] > bv) { bv = sc[s]; bs = s; }

  int* orow = top_idx + (size_t)t * 64;
  for (int j = 0; j < 64; ++j) {
    float v = bv; int n = lane * 8 + bs;
    #pragma unroll
    for (int off = 32; off >= 1; off >>= 1) {
      float ov = __shfl_xor(v, off);
      int   on = __shfl_xor(n, off);
      if (ov > v || (ov == v && on < n)) { v = ov; n = on; }
    }
    if (lane == 0) orow[j] = (v > -INFINITY) ? n : -1;
    if (v > -INFINITY && (n >> 3) == lane) {
      int rs = n & 7;
      #pragma unroll
      for (int s = 0; s < 8; ++s) sc[s] = (s == rs) ? -INFINITY : sc[s];
      bv = -INFINITY; bs = 0;
      #pragma unroll
      for (int s = 0; s < 8; ++s) if (sc[s] > bv) { bv = sc[s]; bs = s; }
    }
  }
}

// ---------------------------------------------------------------------------
// Sparse attention (q bf16, ckv f32 pre-normalized) -> attn bf16 (writes).
// Numerics bit-identical to the verified round-6 kernel.  Phases:
//  B) QK register-blocked 2 heads x 2 keys (round-11, validated)
//  C) row max pm[h] (16 threads, serial fmax — order-independent)
//  D) p = expf(sc - m) computed ONCE per (h,k), overwriting sc in place
//  E) PV with 256 threads (1 head x 8 d), l summed k-ascending as before
// ---------------------------------------------------------------------------
__global__ __launch_bounds__(256) void sparse_attn_k(
    const u16* __restrict__ q,       // (T, 16, 128) bf16
    const float* __restrict__ nckv,  // (512, 128)
    const int* __restrict__ top_idx, // (T, 64)
    u16* __restrict__ attn)          // (T, 16, 128) bf16
{
  int t = blockIdx.x;
  int tid = threadIdx.x;
  __shared__ float skv[64][132];
  __shared__ float qs[16][132];
  __shared__ float sc[16][65];
  __shared__ float pm[16];
  __shared__ int ivals[64];
  if (tid < 64) ivals[tid] = top_idx[(size_t)t * 64 + tid];
  __syncthreads();
  {
    int r = tid >> 2;
    int c0 = (tid & 3) * 32;
    int gi = ivals[r] >= 0 ? ivals[r] : 0;
    #pragma unroll
    for (int i = 0; i < 32; ++i)
      skv[r][c0 + i] = nckv[(size_t)gi * 128 + c0 + i];
  }
  for (int e = tid; e < 2048; e += 256)
    qs[e >> 7][e & 127] = b2f(q[(size_t)t * 2048 + e]);
  __syncthreads();
  // ---- B) QK: thread = (head pair h2, key kk) -> {2h2,2h2+1} x {kk,kk+32}
  {
    int h2 = tid >> 5;          // 0..7
    int kk = tid & 31;          // 0..31
    const float4* q0 = (const float4*)qs[2 * h2];
    const float4* q1 = (const float4*)qs[2 * h2 + 1];
    const float4* k0 = (const float4*)skv[kk];
    const float4* k1 = (const float4*)skv[kk + 32];
    float d00 = 0.f, d01 = 0.f, d10 = 0.f, d11 = 0.f;
    #pragma unroll
    for (int i = 0; i < 32; ++i) {
      float4 a0 = q0[i], a1 = q1[i], b0 = k0[i], b1 = k1[i];
      d00 += a0.x * b0.x + a0.y * b0.y + a0.z * b0.z + a0.w * b0.w;
      d01 += a0.x * b1.x + a0.y * b1.y + a0.z * b1.z + a0.w * b1.w;
      d10 += a1.x * b0.x + a1.y * b0.y + a1.z * b0.z + a1.w * b0.w;
      d11 += a1.x * b1.x + a1.y * b1.y + a1.z * b1.z + a1.w * b1.w;
    }
    bool v0 = ivals[kk] >= 0, v1 = ivals[kk + 32] >= 0;
    sc[2 * h2][kk]          = v0 ? d00 * SCALE : -INFINITY;
    sc[2 * h2][kk + 32]     = v1 ? d01 * SCALE : -INFINITY;
    sc[2 * h2 + 1][kk]      = v0 ? d10 * SCALE : -INFINITY;
    sc[2 * h2 + 1][kk + 32] = v1 ? d11 * SCALE : -INFINITY;
  }
  __syncthreads();
  // ---- C) row max (16 threads, k-ascending fmax as before)
  if (tid < 16) {
    float m = -INFINITY;
    for (int k = 0; k < 64; ++k) m = fmaxf(m, sc[tid][k]);
    pm[tid] = m;
  }
  __syncthreads();
  // ---- D) p = expf(sc - m) once per (h,k), in place
  {
    int h = tid >> 4;
    int k0 = (tid & 15) * 4;
    float m = pm[h];
    if (m > -INFINITY) {
      #pragma unroll
      for (int j = 0; j < 4; ++j)
        sc[h][k0 + j] = expf(sc[h][k0 + j] - m);
    }
  }
  __syncthreads();
  // ---- E) PV: thread = (head, 8-wide d slice); l summed k-ascending
  {
    int h = tid >> 4;
    int d0 = (tid & 15) * 8;
    float o[8] = {};
    if (pm[h] > -INFINITY) {
      float l = 0.f;
      for (int k = 0; k < 64; ++k) {
        float p = sc[h][k];
        l += p;
        const float4* vk = (const float4*)&skv[k][d0];
        float4 va = vk[0], vb = vk[1];
        o[0] += p * va.x; o[1] += p * va.y; o[2] += p * va.z; o[3] += p * va.w;
        o[4] += p * vb.x; o[5] += p * vb.y; o[6] += p * vb.z; o[7] += p * vb.w;
      }
      float inv = 1.0f / l;
      #pragma unroll
      for (int i = 0; i < 8; ++i) o[i] *= inv;
    }
    #pragma unroll
    for (int i = 0; i < 8; ++i)
      attn[(size_t)t * 2048 + h * 128 + d0 + i] = f2b(o[i]);
  }
}

// ---------------------------------------------------------------------------
// Sliding-window attention, bf16 MFMA flash.  Block = (64-q tile, head),
// 4 waves x 16 q-rows.  K swizzled in LDS, V transposed+padded, P via
// per-wave LDS.  attn (bf16) +=.
// ---------------------------------------------------------------------------
__global__ __launch_bounds__(256) void win_attn_mfma_k(
    const u16* __restrict__ q,     // (T, 16, 128) bf16
    const float* __restrict__ kv,  // (T, 512) f32: k@0, v@128
    u16* __restrict__ attn)        // (T, 16, 128) bf16 +=
{
  const int qt = blockIdx.x, hh = blockIdx.y;
  const int tid = threadIdx.x;
  const int wid = tid >> 6, lane = tid & 63;
  const int low = lane & 15, grp = lane >> 4;

  __shared__ __align__(16) u16 Ks[64 * 128];
  __shared__ __align__(16) u16 Vt[128 * 72];
  __shared__ __align__(16) u16 Pl[4][16 * 72];

  u16x8 qf[4];
  {
    const u16* qp = q + (size_t)(qt * 64 + wid * 16 + low) * 2048 + hh * 128 + grp * 8;
    #pragma unroll
    for (int kk = 0; kk < 4; ++kk) qf[kk] = *(const u16x8*)(qp + kk * 32);
  }
  f32x4 zero = {0.f, 0.f, 0.f, 0.f};
  f32x4 o[8];
  #pragma unroll
  for (int dt = 0; dt < 8; ++dt) o[dt] = zero;
  float mrow[4] = {-1e30f, -1e30f, -1e30f, -1e30f};
  float lrow[4] = {0.f, 0.f, 0.f, 0.f};

  const int kt0 = qt >= 4 ? qt - 4 : 0;
  const int srow = tid >> 2;
  const int scol = (tid & 3) * 32;
  for (int kt = kt0; kt <= qt; ++kt) {
    __syncthreads();
    {
      const float* gk = kv + (size_t)(kt * 64 + srow) * 512 + scol;
      u16 tmp[32];
      #pragma unroll
      for (int i = 0; i < 32; i += 4) {
        float4 v = *(const float4*)(gk + i);
        tmp[i] = f2b(v.x); tmp[i+1] = f2b(v.y); tmp[i+2] = f2b(v.z); tmp[i+3] = f2b(v.w);
      }
      #pragma unroll
      for (int j = 0; j < 4; ++j) {
        int c = scol + j * 8;
        *(u16x8*)(Ks + srow * 128 + (c ^ ((srow & 7) << 3))) = *(const u16x8*)(tmp + j * 8);
      }
      const float* gv = gk + 128;
      #pragma unroll
      for (int i = 0; i < 32; i += 4) {
        float4 v = *(const float4*)(gv + i);
        Vt[(scol + i + 0) * 72 + srow] = f2b(v.x);
        Vt[(scol + i + 1) * 72 + srow] = f2b(v.y);
        Vt[(scol + i + 2) * 72 + srow] = f2b(v.z);
        Vt[(scol + i + 3) * 72 + srow] = f2b(v.w);
      }
    }
    __syncthreads();
    f32x4 s[4];
    #pragma unroll
    for (int n = 0; n < 4; ++n) {
      s[n] = zero;
      int krow = n * 16 + low;
      #pragma unroll
      for (int kk = 0; kk < 4; ++kk) {
        u16x8 kf = *(const u16x8*)(Ks + krow * 128 + ((kk * 32 + grp * 8) ^ ((krow & 7) << 3)));
        mfma16(s[n], qf[kk], kf);
      }
    }
    asm volatile("s_nop 7\n\ts_nop 7");
    const int qg = qt * 64 + wid * 16 + grp * 4;
    #pragma unroll
    for (int n = 0; n < 4; ++n) {
      int kg = kt * 64 + n * 16 + low;
      #pragma unroll
      for (int r = 0; r < 4; ++r) {
        bool ok = (kg <= qg + r) && (kg > qg + r - 256);
        s[n][r] = ok ? s[n][r] * SCALE : -1e30f;
      }
    }
    float p[4][4];
    #pragma unroll
    for (int r = 0; r < 4; ++r) {
      float rm = fmaxf(fmaxf(s[0][r], s[1][r]), fmaxf(s[2][r], s[3][r]));
      rm = fmaxf(rm, __shfl_xor(rm, 1));
      rm = fmaxf(rm, __shfl_xor(rm, 2));
      rm = fmaxf(rm, __shfl_xor(rm, 4));
      rm = fmaxf(rm, __shfl_xor(rm, 8));
      float nm = fmaxf(mrow[r], rm);
      float f = __expf(mrow[r] - nm);
      mrow[r] = nm;
      float ps = 0.f;
      #pragma unroll
      for (int n = 0; n < 4; ++n) { p[n][r] = __expf(s[n][r] - nm); ps += p[n][r]; }
      ps += __shfl_xor(ps, 1); ps += __shfl_xor(ps, 2);
      ps += __shfl_xor(ps, 4); ps += __shfl_xor(ps, 8);
      lrow[r] = lrow[r] * f + ps;
      #pragma unroll
      for (int dt = 0; dt < 8; ++dt) o[dt][r] *= f;
    }
    u16* pw = Pl[wid];
    #pragma unroll
    for (int n = 0; n < 4; ++n)
      #pragma unroll
      for (int r = 0; r < 4; ++r)
        pw[(grp * 4 + r) * 72 + n * 16 + low] = f2b(p[n][r]);
    #pragma unroll
    for (int kk2 = 0; kk2 < 2; ++kk2) {
      u16x8 pa = *(const u16x8*)(pw + low * 72 + kk2 * 32 + grp * 8);
      #pragma unroll
      for (int dt = 0; dt < 8; ++dt) {
        u16x8 vf = *(const u16x8*)(Vt + (dt * 16 + low) * 72 + kk2 * 32 + grp * 8);
        mfma16(o[dt], pa, vf);
      }
    }
  }
  asm volatile("s_nop 7\n\ts_nop 7");
  float linv[4];
  #pragma unroll
  for (int r = 0; r < 4; ++r) linv[r] = 1.0f / lrow[r];
  u16* ap = attn + (size_t)(qt * 64 + wid * 16 + grp * 4) * 2048 + hh * 128 + low;
  #pragma unroll
  for (int r = 0; r < 4; ++r)
    #pragma unroll
    for (int dt = 0; dt < 8; ++dt) {
      size_t idx = (size_t)r * 2048 + dt * 16;
      ap[idx] = f2b(b2f(ap[idx]) + o[dt][r] * linv[r]);
    }
}

// ---------------------------------------------------------------------------
extern "C" void kernel_launch(void* const* d_in, const int* in_sizes, int n_in,
                              void* d_out, int out_size, void* d_ws, size_t ws_size,
                              hipStream_t stream)
{
  const float* h        = (const float*)d_in[0];
  const float* w_qc     = (const float*)d_in[1];
  const float* w_qup    = (const float*)d_in[2];
  const float* kvc_w    = (const float*)d_in[3];
  const float* kvc_wz   = (const float*)d_in[4];
  const float* kvc_bias = (const float*)d_in[5];
  const float* k_proj_w = (const float*)d_in[6];
  const float* v_proj_w = (const float*)d_in[7];
  const float* idx_c_w  = (const float*)d_in[8];
  const float* idx_c_wz = (const float*)d_in[9];
  const float* idx_c_bias = (const float*)d_in[10];
  const float* w_dq     = (const float*)d_in[11];
  const float* w_iuq    = (const float*)d_in[12];
  const float* w_w      = (const float*)d_in[13];
  const float* q_norm_w = (const float*)d_in[14];
  const float* k_norm_w = (const float*)d_in[15];
  const float* group_w  = (const float*)d_in[16];
  const float* final_w  = (const float*)d_in[17];
  float* out = (float*)d_out;

  float* ws = (float*)d_ws;
  size_t off = 0;
  auto alloc = [&](size_t nfloats) { float* p = ws + off; off += nfloats; return p; };
  float* cosT  = alloc((size_t)T_LEN * 32);
  float* sinT  = alloc((size_t)T_LEN * 32);
  u16* qb      = (u16*)alloc((size_t)T_LEN * 1024);
  u16* attnb   = (u16*)alloc((size_t)T_LEN * 1024);
  u16* hb      = (u16*)alloc((size_t)T_LEN * 1024);
  float* kvout = alloc((size_t)T_LEN * 512);
  float* ibuf  = alloc((size_t)T_LEN * 228);
  float* kT    = alloc((size_t)64 * NBLK);
  float* ckv   = alloc((size_t)NBLK * 128);
  float* qib   = alloc((size_t)T_LEN * 256);
  int*   topi  = (int*)alloc((size_t)T_LEN * 64);
  u16* w_qcT   = (u16*)alloc((size_t)512 * 1024);     // rows 0-511 of fused B
  u16* kvT     = (u16*)alloc((size_t)512 * 1024);     // rows 512-1023 (contiguous!)
  u16* w_qupT  = (u16*)alloc((size_t)2048 * 256);
  u16* gwT     = (u16*)alloc((size_t)4 * 512 * 256);
  u16* fwT     = (u16*)alloc((size_t)2048 * 1024);
  float* part  = alloc((size_t)4 * T_LEN * NIDX);     // split-K partials
  float* Bcat  = (float*)attnb;                       // 2048 x 196 f32
  u16* hq1b    = (u16*)((float*)attnb + 524288);
  u16* og      = qb;

  rope_cs_k<<<(T_LEN * 32 + 255) / 256, 256, 0, stream>>>(cosT, sinT);
  castk<<<(T_LEN * 2048 / 4 + 255) / 256, 256, 0, stream>>>(h, hb, T_LEN * 2048 / 4);
  tcast_k<<<dim3(16, 64), 256, 0, stream>>>(w_qc, w_qcT, 2048, 512);
  tcast_k<<<dim3(4, 64), 256, 0, stream>>>(k_proj_w, kvT + (size_t)0 * 128 * 2048, 2048, 128);
  tcast_k<<<dim3(4, 64), 256, 0, stream>>>(v_proj_w, kvT + (size_t)1 * 128 * 2048, 2048, 128);
  tcast_k<<<dim3(4, 64), 256, 0, stream>>>(kvc_w,    kvT + (size_t)2 * 128 * 2048, 2048, 128);
  tcast_k<<<dim3(4, 64), 256, 0, stream>>>(kvc_wz,   kvT + (size_t)3 * 128 * 2048, 2048, 128);
  tcast_k<<<dim3(64, 16), 256, 0, stream>>>(w_qup, w_qupT, 512, 2048);
  for (int g = 0; g < 4; ++g)
    tcast_k<<<dim3(16, 16), 256, 0, stream>>>(group_w + (size_t)g * 512 * 512,
                                              gwT + (size_t)g * 512 * 512, 512, 512);
  tcast_k<<<dim3(64, 64), 256, 0, stream>>>(final_w, fwT, 2048, 2048);
  concat_idx_k<<<(2048 * NIDX + 255) / 256, 256, 0, stream>>>(idx_c_w, idx_c_wz, w_dq, w_w, Bcat);

  // fused qc + k|v|kvc projections (one N=1024 bf16 MFMA GEMM, split outputs)
  bgemm_qckv_k<<<dim3(8, 64), 256, 0, stream>>>(hb, w_qcT, hq1b, kvout);

  // q chain tail
  bgemm_k<1><<<dim3(16, 64), 256, 0, stream>>>(hq1b, 512, w_qupT, 512, qb, 2048, 512);
  q_rope_norm_k<<<T_LEN * 4, 256, 0, stream>>>(qb, cosT, sinT, q_norm_w);

  // sliding-window k norm/rope + kv compression (normalize f32 rows in place)
  k_norm_rope_k<<<T_LEN / 4, 256, 0, stream>>>(kvout, cosT, sinT, k_norm_w);
  compress_k<<<(NBLK * 128 + 255) / 256, 256, 0, stream>>>(
      kvout + 256, kvout + 384, 512, kvc_bias, ckv, 128, 128, 1);
  rms_rows_k<<<NBLK / 4, 256, 0, stream>>>(ckv, k_norm_w);

  // index path (f32 exact for selection stability; split-K for occupancy)
  sgemm_splitk_k<<<dim3(4, 64, 4), 256, 0, stream>>>(h, HID, Bcat, NIDX, part, NIDX, T_LEN, NIDX, 512);
  reduce4_k<<<(T_LEN * NIDX + 255) / 256, 256, 0, stream>>>(part, NIDX, ibuf, 228, T_LEN);
  compress_k<<<(NBLK * 64 + 255) / 256, 256, 0, stream>>>(
      ibuf, ibuf + 64, 228, idx_c_bias, kT, 64, 1, NBLK);
  sgemm_k<<<dim3(4, 128), 256, 0, stream>>>(ibuf + 128, 228, w_iuq, 256, qib, 256, T_LEN, 256, 64);
  topk_k<<<T_LEN / 4, 256, 0, stream>>>(qib, ibuf + 192, 228, kT, topi);

  // attention
  sparse_attn_k<<<T_LEN, 256, 0, stream>>>(qb, ckv, topi, attnb);
  win_attn_mfma_k<<<dim3(T_LEN / 64, 16), 256, 0, stream>>>(qb, kvout, attnb);

  // output projections (bf16 MFMA): fused group projection, then final
  bgemm_group_k<<<dim3(4, 64, 4), 256, 0, stream>>>(attnb, gwT, og);
  bgemm_k<0><<<dim3(16, 64), 256, 0, stream>>>(og, 2048, fwT, 2048, out, 2048, 2048);
}

// Round 14
// 910.593 us; speedup vs baseline: 1.0289x; 1.0289x over previous
//
#include <hip/hip_runtime.h>
#include <math.h>

#define T_LEN 8192
#define HID   2048
#define NHEAD 16
#define HD    128
#define NBLK  512
#define NIDX  196                    // 64+64+64+4 used index-path columns
#define SCALE 0.08838834764831845f   // 1/sqrt(128)

typedef unsigned short u16;
typedef unsigned short u16x8 __attribute__((ext_vector_type(8)));
typedef float f32x4 __attribute__((ext_vector_type(4)));

// ---- bf16 <-> f32 via bit ops (RNE) ----
__device__ __forceinline__ u16 f2b(float f) {
  unsigned int u = __float_as_uint(f);
  return (u16)((u + 0x7fffu + ((u >> 16) & 1u)) >> 16);
}
__device__ __forceinline__ float b2f(u16 s) {
  return __uint_as_float(((unsigned int)s) << 16);
}

// ---- async global->LDS, 16B per lane (dest must be wave-linear) ----
__device__ __forceinline__ void gload16(const u16* g, u16* l) {
  __builtin_amdgcn_global_load_lds(
      (__attribute__((address_space(1))) void*)(uintptr_t)g,
      (__attribute__((address_space(3))) void*)(unsigned int)(uintptr_t)l,
      16, 0, 0);
}

// ---- MFMA 16x16x32 bf16 via inline asm (D/C tied) ----
__device__ __forceinline__ void mfma16(f32x4& d, u16x8 a, u16x8 b) {
  asm("v_mfma_f32_16x16x32_bf16 %0, %1, %2, %0" : "+v"(d) : "v"(a), "v"(b));
}

// ---------------------------------------------------------------------------
// bf16 MFMA GEMM: C[M,N] = A[M,K] @ Bt[N,K]^T.  m97 structure, 128x128 tile.
// ---------------------------------------------------------------------------
template<int OUT_BF16>
__global__ __launch_bounds__(256) void bgemm_k(
    const u16* __restrict__ A, int lda,
    const u16* __restrict__ Bt, int ldb,
    void* __restrict__ Cp, int ldc, int K)
{
  __shared__ __align__(16) u16 Al[128 * 32];
  __shared__ __align__(16) u16 Bl[128 * 32];
  const int tid = threadIdx.x;
  const int lane = tid & 63;
  const int bm = blockIdx.y * 128;
  const int bn = blockIdx.x * 128;
  const int wr = ((tid >> 6) >> 1) * 64;
  const int wc = ((tid >> 6) & 1) * 64;
  const int r0 = tid >> 2;
  const int c0 = (tid & 3) * 8;
  const u16* ga0 = A  + (size_t)(bm + r0) * lda + c0;
  const u16* ga1 = ga0 + (size_t)64 * lda;
  const u16* gb0 = Bt + (size_t)(bn + r0) * ldb + c0;
  const u16* gb1 = gb0 + (size_t)64 * ldb;
  u16* la0 = Al + tid * 8;
  u16* la1 = Al + (tid + 256) * 8;
  u16* lb0 = Bl + tid * 8;
  u16* lb1 = Bl + (tid + 256) * 8;

  f32x4 zero = {0.f, 0.f, 0.f, 0.f};
  f32x4 acc[4][4];
  #pragma unroll
  for (int m = 0; m < 4; ++m)
    #pragma unroll
    for (int n = 0; n < 4; ++n) acc[m][n] = zero;

  const int ar = wr + (lane & 15);
  const int br = wc + (lane & 15);
  const int ko = (lane >> 4) * 8;

  for (int k0 = 0; k0 < K; k0 += 32) {
    gload16(ga0 + k0, la0);
    gload16(ga1 + k0, la1);
    gload16(gb0 + k0, lb0);
    gload16(gb1 + k0, lb1);
    __syncthreads();
    u16x8 af[4], bfr[4];
    #pragma unroll
    for (int m = 0; m < 4; ++m)
      af[m] = *(const u16x8*)(Al + (size_t)(ar + m * 16) * 32 + ko);
    #pragma unroll
    for (int n = 0; n < 4; ++n)
      bfr[n] = *(const u16x8*)(Bl + (size_t)(br + n * 16) * 32 + ko);
    #pragma unroll
    for (int m = 0; m < 4; ++m)
      #pragma unroll
      for (int n = 0; n < 4; ++n) mfma16(acc[m][n], af[m], bfr[n]);
    __syncthreads();
  }
  asm volatile("s_nop 7\n\ts_nop 7");
  const int er = (lane >> 4) * 4;
  const int ec = lane & 15;
  #pragma unroll
  for (int m = 0; m < 4; ++m)
    #pragma unroll
    for (int n = 0; n < 4; ++n)
      #pragma unroll
      for (int r = 0; r < 4; ++r) {
        size_t idx = (size_t)(bm + wr + m * 16 + er + r) * ldc + (bn + wc + n * 16 + ec);
        if (OUT_BF16) ((u16*)Cp)[idx] = f2b(acc[m][n][r]);
        else          ((float*)Cp)[idx] = acc[m][n][r];
      }
}

// ---------------------------------------------------------------------------
// Fused qc|kv projection GEMM: A = hb (8192x2048), Bt = [w_qcT(512) ; kvT(512)]
// (1024x2048).  Cols 0-511 -> Cq bf16 (ld 512); cols 512-1023 -> Ckv f32 (ld 512).
// ---------------------------------------------------------------------------
__global__ __launch_bounds__(256) void bgemm_qckv_k(
    const u16* __restrict__ A, const u16* __restrict__ Bt,
    u16* __restrict__ Cq, float* __restrict__ Ckv)
{
  __shared__ __align__(16) u16 Al[128 * 32];
  __shared__ __align__(16) u16 Bl[128 * 32];
  const int tid = threadIdx.x;
  const int lane = tid & 63;
  const int bm = blockIdx.y * 128;
  const int bn = blockIdx.x * 128;
  const int wr = ((tid >> 6) >> 1) * 64;
  const int wc = ((tid >> 6) & 1) * 64;
  const int r0 = tid >> 2;
  const int c0 = (tid & 3) * 8;
  const u16* ga0 = A  + (size_t)(bm + r0) * 2048 + c0;
  const u16* ga1 = ga0 + (size_t)64 * 2048;
  const u16* gb0 = Bt + (size_t)(bn + r0) * 2048 + c0;
  const u16* gb1 = gb0 + (size_t)64 * 2048;
  u16* la0 = Al + tid * 8;
  u16* la1 = Al + (tid + 256) * 8;
  u16* lb0 = Bl + tid * 8;
  u16* lb1 = Bl + (tid + 256) * 8;

  f32x4 zero = {0.f, 0.f, 0.f, 0.f};
  f32x4 acc[4][4];
  #pragma unroll
  for (int m = 0; m < 4; ++m)
    #pragma unroll
    for (int n = 0; n < 4; ++n) acc[m][n] = zero;

  const int ar = wr + (lane & 15);
  const int br = wc + (lane & 15);
  const int ko = (lane >> 4) * 8;

  for (int k0 = 0; k0 < 2048; k0 += 32) {
    gload16(ga0 + k0, la0);
    gload16(ga1 + k0, la1);
    gload16(gb0 + k0, lb0);
    gload16(gb1 + k0, lb1);
    __syncthreads();
    u16x8 af[4], bfr[4];
    #pragma unroll
    for (int m = 0; m < 4; ++m)
      af[m] = *(const u16x8*)(Al + (size_t)(ar + m * 16) * 32 + ko);
    #pragma unroll
    for (int n = 0; n < 4; ++n)
      bfr[n] = *(const u16x8*)(Bl + (size_t)(br + n * 16) * 32 + ko);
    #pragma unroll
    for (int m = 0; m < 4; ++m)
      #pragma unroll
      for (int n = 0; n < 4; ++n) mfma16(acc[m][n], af[m], bfr[n]);
    __syncthreads();
  }
  asm volatile("s_nop 7\n\ts_nop 7");
  const int er = (lane >> 4) * 4;
  const int ec = lane & 15;
  if (bn < 512) {
    #pragma unroll
    for (int m = 0; m < 4; ++m)
      #pragma unroll
      for (int n = 0; n < 4; ++n)
        #pragma unroll
        for (int r = 0; r < 4; ++r)
          Cq[(size_t)(bm + wr + m * 16 + er + r) * 512 + (bn + wc + n * 16 + ec)]
              = f2b(acc[m][n][r]);
  } else {
    #pragma unroll
    for (int m = 0; m < 4; ++m)
      #pragma unroll
      for (int n = 0; n < 4; ++n)
        #pragma unroll
        for (int r = 0; r < 4; ++r)
          Ckv[(size_t)(bm + wr + m * 16 + er + r) * 512 + (bn - 512 + wc + n * 16 + ec)]
              = acc[m][n][r];
  }
}

// ---------------------------------------------------------------------------
// Fused group projection: z = group.  A = attnb + z*512 (ld 2048), K=512,
// Bt = gwT + z*512*512, C = og + z*512 (ld 2048) bf16.
// ---------------------------------------------------------------------------
__global__ __launch_bounds__(256) void bgemm_group_k(
    const u16* __restrict__ Ab, const u16* __restrict__ gw,
    u16* __restrict__ Cb)
{
  __shared__ __align__(16) u16 Al[128 * 32];
  __shared__ __align__(16) u16 Bl[128 * 32];
  const int tid = threadIdx.x;
  const int lane = tid & 63;
  const int bm = blockIdx.y * 128;
  const int bn = blockIdx.x * 128;
  const int g  = blockIdx.z;
  const u16* A  = Ab + (size_t)g * 512;
  const u16* Bt = gw + (size_t)g * 512 * 512;
  u16* C = Cb + (size_t)g * 512;
  const int wr = ((tid >> 6) >> 1) * 64;
  const int wc = ((tid >> 6) & 1) * 64;
  const int r0 = tid >> 2;
  const int c0 = (tid & 3) * 8;
  const u16* ga0 = A  + (size_t)(bm + r0) * 2048 + c0;
  const u16* ga1 = ga0 + (size_t)64 * 2048;
  const u16* gb0 = Bt + (size_t)(bn + r0) * 512 + c0;
  const u16* gb1 = gb0 + (size_t)64 * 512;
  u16* la0 = Al + tid * 8;
  u16* la1 = Al + (tid + 256) * 8;
  u16* lb0 = Bl + tid * 8;
  u16* lb1 = Bl + (tid + 256) * 8;

  f32x4 zero = {0.f, 0.f, 0.f, 0.f};
  f32x4 acc[4][4];
  #pragma unroll
  for (int m = 0; m < 4; ++m)
    #pragma unroll
    for (int n = 0; n < 4; ++n) acc[m][n] = zero;

  const int ar = wr + (lane & 15);
  const int br = wc + (lane & 15);
  const int ko = (lane >> 4) * 8;

  for (int k0 = 0; k0 < 512; k0 += 32) {
    gload16(ga0 + k0, la0);
    gload16(ga1 + k0, la1);
    gload16(gb0 + k0, lb0);
    gload16(gb1 + k0, lb1);
    __syncthreads();
    u16x8 af[4], bfr[4];
    #pragma unroll
    for (int m = 0; m < 4; ++m)
      af[m] = *(const u16x8*)(Al + (size_t)(ar + m * 16) * 32 + ko);
    #pragma unroll
    for (int n = 0; n < 4; ++n)
      bfr[n] = *(const u16x8*)(Bl + (size_t)(br + n * 16) * 32 + ko);
    #pragma unroll
    for (int m = 0; m < 4; ++m)
      #pragma unroll
      for (int n = 0; n < 4; ++n) mfma16(acc[m][n], af[m], bfr[n]);
    __syncthreads();
  }
  asm volatile("s_nop 7\n\ts_nop 7");
  const int er = (lane >> 4) * 4;
  const int ec = lane & 15;
  #pragma unroll
  for (int m = 0; m < 4; ++m)
    #pragma unroll
    for (int n = 0; n < 4; ++n)
      #pragma unroll
      for (int r = 0; r < 4; ++r)
        C[(size_t)(bm + wr + m * 16 + er + r) * 2048 + (bn + wc + n * 16 + ec)]
            = f2b(acc[m][n][r]);
}

// ---------------------------------------------------------------------------
// f32 GEMM with split-K, 64x64 tile, 4x4 micro-tile (round-12 verified
// shape), BK=32 (barriers halved).  Per-output-element K-summation order
// is global-k ascending — bit-identical to the BK=16 version.
// ---------------------------------------------------------------------------
__global__ __launch_bounds__(256) void sgemm_splitk_k(
    const float* __restrict__ A, int lda,
    const float* __restrict__ B, int ldb,
    float* __restrict__ P, int ldc,
    int M, int N, int kchunk)
{
  __shared__ __align__(16) float As[32][68];
  __shared__ __align__(16) float Bs[32][68];
  const int bm = blockIdx.y * 64;
  const int bn = blockIdx.x * 64;
  const int kb = blockIdx.z * kchunk;
  float* C = P + (size_t)blockIdx.z * M * ldc;
  const int tid = threadIdx.x;
  const int tx = tid & 15;
  const int ty = tid >> 4;
  float acc[4][4] = {};
  for (int k0 = 0; k0 < kchunk; k0 += 32) {
    #pragma unroll
    for (int i = 0; i < 8; ++i) {
      int f = tid + i * 256;           // 0..2047 -> A tile 64x32
      int r = f >> 5, c = f & 31;
      float v = 0.f;
      int gr = bm + r;
      if (gr < M) v = A[(size_t)gr * lda + (kb + k0 + c)];
      As[c][r] = v;
    }
    #pragma unroll
    for (int i = 0; i < 8; ++i) {
      int f = tid + i * 256;           // 0..2047 -> B tile 32x64
      int r = f >> 6, c = f & 63;
      float v = 0.f;
      int gc = bn + c;
      if (gc < N) v = B[(size_t)(kb + k0 + r) * ldb + gc];
      Bs[r][c] = v;
    }
    __syncthreads();
    #pragma unroll
    for (int kk = 0; kk < 32; ++kk) {
      float4 a = *(const float4*)&As[kk][ty * 4];
      float4 b = *(const float4*)&Bs[kk][tx * 4];
      float av[4] = {a.x, a.y, a.z, a.w};
      float bv[4] = {b.x, b.y, b.z, b.w};
      #pragma unroll
      for (int i = 0; i < 4; ++i)
        #pragma unroll
        for (int j = 0; j < 4; ++j) acc[i][j] += av[i] * bv[j];
    }
    __syncthreads();
  }
  #pragma unroll
  for (int i = 0; i < 4; ++i) {
    int gr = bm + ty * 4 + i;
    if (gr >= M) continue;
    #pragma unroll
    for (int j = 0; j < 4; ++j) {
      int gc = bn + tx * 4 + j;
      if (gc < N) C[(size_t)gr * ldc + gc] = acc[i][j];
    }
  }
}

// ---- sum 4 split-K partials [4][M][ldp] -> out[M][ldo] ----
__global__ void reduce4_k(const float* __restrict__ P, int ldp,
                          float* __restrict__ o, int ldo, int M)
{
  int i = blockIdx.x * 256 + threadIdx.x;
  if (i >= M * ldp) return;
  int r = i / ldp, c = i % ldp;
  size_t st = (size_t)M * ldp;
  float v = P[i] + P[i + st] + P[i + 2 * st] + P[i + 3 * st];
  o[(size_t)r * ldo + c] = v;
}

// ---------------------------------------------------------------------------
// Generic tiled f32 GEMM (small-K qib GEMM), vectorized LDS reads.
// ---------------------------------------------------------------------------
__global__ __launch_bounds__(256) void sgemm_k(
    const float* __restrict__ A, int lda,
    const float* __restrict__ B, int ldb,
    float* __restrict__ C, int ldc,
    int M, int N, int K)
{
  __shared__ __align__(16) float As[16][68];
  __shared__ __align__(16) float Bs[16][68];
  const int bm = blockIdx.y * 64;
  const int bn = blockIdx.x * 64;
  const int tid = threadIdx.x;
  const int tx = tid & 15;
  const int ty = tid >> 4;
  float acc[4][4] = {};
  for (int k0 = 0; k0 < K; k0 += 16) {
    #pragma unroll
    for (int i = 0; i < 4; ++i) {
      int f = tid + i * 256;
      int r = f >> 4, c = f & 15;
      float v = 0.f;
      int gr = bm + r, gc = k0 + c;
      if (gr < M && gc < K) v = A[(size_t)gr * lda + gc];
      As[c][r] = v;
    }
    #pragma unroll
    for (int i = 0; i < 4; ++i) {
      int f = tid + i * 256;
      int r = f >> 6, c = f & 63;
      float v = 0.f;
      int gr = k0 + r, gc = bn + c;
      if (gr < K && gc < N) v = B[(size_t)gr * ldb + gc];
      Bs[r][c] = v;
    }
    __syncthreads();
    #pragma unroll
    for (int kk = 0; kk < 16; ++kk) {
      float4 a = *(const float4*)&As[kk][ty * 4];
      float4 b = *(const float4*)&Bs[kk][tx * 4];
      float av[4] = {a.x, a.y, a.z, a.w};
      float bv[4] = {b.x, b.y, b.z, b.w};
      #pragma unroll
      for (int i = 0; i < 4; ++i)
        #pragma unroll
        for (int j = 0; j < 4; ++j) acc[i][j] += av[i] * bv[j];
    }
    __syncthreads();
  }
  #pragma unroll
  for (int i = 0; i < 4; ++i) {
    int gr = bm + ty * 4 + i;
    if (gr >= M) continue;
    #pragma unroll
    for (int j = 0; j < 4; ++j) {
      int gc = bn + tx * 4 + j;
      if (gc < N) C[(size_t)gr * ldc + gc] = acc[i][j];
    }
  }
}

// ---------------------------------------------------------------------------
// f32 -> bf16 cast (4 elems/thread)
// ---------------------------------------------------------------------------
__global__ void castk(const float* __restrict__ in, u16* __restrict__ out, int n4)
{
  int i = blockIdx.x * 256 + threadIdx.x;
  if (i >= n4) return;
  float4 v = ((const float4*)in)[i];
  unsigned int lo = (unsigned int)f2b(v.x) | ((unsigned int)f2b(v.y) << 16);
  unsigned int hi = (unsigned int)f2b(v.z) | ((unsigned int)f2b(v.w) << 16);
  ((uint2*)out)[i] = make_uint2(lo, hi);
}

// ---------------------------------------------------------------------------
// transpose + cast: in f32 [R][C] -> out bf16 [C][R]
// ---------------------------------------------------------------------------
__global__ __launch_bounds__(256) void tcast_k(
    const float* __restrict__ in, u16* __restrict__ outT, int R, int C)
{
  __shared__ float t[32][33];
  int bc = blockIdx.x * 32, br = blockIdx.y * 32;
  int lx = threadIdx.x & 31, ly = threadIdx.x >> 5;
  #pragma unroll
  for (int i = 0; i < 32; i += 8) {
    int r = br + ly + i, c = bc + lx;
    t[ly + i][lx] = (r < R && c < C) ? in[(size_t)r * C + c] : 0.f;
  }
  __syncthreads();
  #pragma unroll
  for (int i = 0; i < 32; i += 8) {
    int c = bc + ly + i, r = br + lx;
    if (c < C && r < R) outT[(size_t)c * R + r] = f2b(t[lx][ly + i]);
  }
}

// ---------------------------------------------------------------------------
// Concat the 4 index-path weights into Bcat f32 (2048 x 196)
// ---------------------------------------------------------------------------
__global__ void concat_idx_k(const float* __restrict__ a, const float* __restrict__ b,
                             const float* __restrict__ c, const float* __restrict__ d,
                             float* __restrict__ o)
{
  int i = blockIdx.x * 256 + threadIdx.x;
  if (i >= 2048 * NIDX) return;
  int r = i / NIDX, col = i % NIDX;
  float v = (col < 64)  ? a[r * 64 + col]
          : (col < 128) ? b[r * 64 + col - 64]
          : (col < 192) ? c[r * 64 + col - 128]
          :               d[r * 4 + col - 192];
  o[i] = v;
}

// ---------------------------------------------------------------------------
// RoPE cos/sin tables: (T, 32) each.
// ---------------------------------------------------------------------------
__global__ void rope_cs_k(float* __restrict__ ct, float* __restrict__ st)
{
  int idx = blockIdx.x * blockDim.x + threadIdx.x;
  if (idx >= T_LEN * 32) return;
  int t = idx >> 5, i = idx & 31;
  float inv = powf(10000.0f, -(float)(2 * i) / 64.0f);
  float ang = (float)t * inv;
  ct[idx] = cosf(ang);
  st[idx] = sinf(ang);
}

// ---------------------------------------------------------------------------
// q (bf16, row = t*16+h): rope then rmsnorm, in place. 4 rows/block (1/wave).
// ---------------------------------------------------------------------------
__global__ __launch_bounds__(256) void q_rope_norm_k(
    u16* __restrict__ q, const float* __restrict__ ct,
    const float* __restrict__ st, const float* __restrict__ w)
{
  int wid = threadIdx.x >> 6;
  int row = blockIdx.x * 4 + wid;
  int t = row >> 4;
  int lane = threadIdx.x & 63;
  __shared__ float ls[4][128];
  u16* rp = q + (size_t)row * 128;
  ls[wid][lane] = b2f(rp[lane]);
  ls[wid][lane + 64] = b2f(rp[lane + 64]);
  __syncthreads();
  float v0;
  if (lane < 32) {
    float c = ct[t * 32 + lane], s = st[t * 32 + lane];
    v0 = ls[wid][lane] * c - ls[wid][lane + 32] * s;
  } else {
    int i = lane - 32;
    float c = ct[t * 32 + i], s = st[t * 32 + i];
    v0 = ls[wid][i] * s + ls[wid][lane] * c;
  }
  float v1 = ls[wid][lane + 64];
  float ss = v0 * v0 + v1 * v1;
  #pragma unroll
  for (int off = 1; off < 64; off <<= 1) ss += __shfl_xor(ss, off);
  float rn = 1.0f / sqrtf(ss / 128.0f + 1e-6f);
  rp[lane] = f2b(v0 * rn * w[lane]);
  rp[lane + 64] = f2b(v1 * rn * w[lane + 64]);
}

// ---------------------------------------------------------------------------
// sw_k inside kvout (f32, row stride 512, cols 0..127): rmsnorm then rope.
// ---------------------------------------------------------------------------
__global__ __launch_bounds__(256) void k_norm_rope_k(
    float* __restrict__ kv, const float* __restrict__ ct,
    const float* __restrict__ st, const float* __restrict__ w)
{
  int wid = threadIdx.x >> 6;
  int t = blockIdx.x * 4 + wid;
  int lane = threadIdx.x & 63;
  __shared__ float ls[4][128];
  float* rp = kv + (size_t)t * 512;
  float a = rp[lane], b = rp[lane + 64];
  float ss = a * a + b * b;
  #pragma unroll
  for (int off = 1; off < 64; off <<= 1) ss += __shfl_xor(ss, off);
  float rn = 1.0f / sqrtf(ss / 128.0f + 1e-6f);
  a *= rn * w[lane];
  b *= rn * w[lane + 64];
  ls[wid][lane] = a;
  ls[wid][lane + 64] = b;
  __syncthreads();
  float v0;
  if (lane < 32) {
    float c = ct[t * 32 + lane], s = st[t * 32 + lane];
    v0 = ls[wid][lane] * c - ls[wid][lane + 32] * s;
  } else {
    int i = lane - 32;
    float c = ct[t * 32 + i], s = st[t * 32 + i];
    v0 = ls[wid][i] * s + ls[wid][lane] * c;
  }
  rp[lane] = v0;
  rp[lane + 64] = b;
}

// ---------------------------------------------------------------------------
// rmsnorm 128-wide f32 rows in place.  4 rows per block (1/wave).
// ---------------------------------------------------------------------------
__global__ __launch_bounds__(256) void rms_rows_k(
    float* __restrict__ x, const float* __restrict__ w)
{
  int r = blockIdx.x * 4 + (threadIdx.x >> 6);
  int lane = threadIdx.x & 63;
  float* rp = x + (size_t)r * 128;
  float a = rp[lane], b = rp[lane + 64];
  float ss = a * a + b * b;
  #pragma unroll
  for (int off = 1; off < 64; off <<= 1) ss += __shfl_xor(ss, off);
  float rn = 1.0f / sqrtf(ss / 128.0f + 1e-6f);
  rp[lane] = a * rn * w[lane];
  rp[lane + 64] = b * rn * w[lane + 64];
}

// ---------------------------------------------------------------------------
// compress with input row-stride ldin: out[n*sn + d*sd]
// ---------------------------------------------------------------------------
__global__ void compress_k(
    const float* __restrict__ c, const float* __restrict__ z, int ldin,
    const float* __restrict__ bias, float* __restrict__ out,
    int D, int sn, int sd)
{
  int idx = blockIdx.x * blockDim.x + threadIdx.x;
  if (idx >= NBLK * D) return;
  int n = idx / D, d = idx % D;
  float zb[16];
  float mx = -INFINITY;
  #pragma unroll
  for (int m = 0; m < 16; ++m) {
    float v = z[(size_t)(n * 16 + m) * ldin + d] + bias[m * D + d];
    zb[m] = v;
    mx = fmaxf(mx, v);
  }
  float s = 0.f;
  #pragma unroll
  for (int m = 0; m < 16; ++m) { zb[m] = expf(zb[m] - mx); s += zb[m]; }
  float acc = 0.f;
  #pragma unroll
  for (int m = 0; m < 16; ++m) acc += zb[m] * c[(size_t)(n * 16 + m) * ldin + d];
  out[(size_t)n * sn + (size_t)d * sd] = acc / s;
}

// ---------------------------------------------------------------------------
// Top-64 per t, fully in-register, one wave per t (4 waves/block).
// ---------------------------------------------------------------------------
__global__ __launch_bounds__(256) void topk_k(
    const float* __restrict__ qi,    // (T, 4, 64)
    const float* __restrict__ wih, int wst,
    const float* __restrict__ kT,    // (64, 512)
    int* __restrict__ top_idx)       // (T, 64)
{
  const int wid = threadIdx.x >> 6;
  const int lane = threadIdx.x & 63;
  const int t = blockIdx.x * 4 + wid;
  __shared__ float qs[4][256];
  for (int i = lane; i < 256; i += 64) qs[wid][i] = qi[(size_t)t * 256 + i];
  float wh[4];
  #pragma unroll
  for (int h = 0; h < 4; ++h) wh[h] = wih[(size_t)t * wst + h];
  __syncthreads();

  float d[4][8] = {};
  for (int cc = 0; cc < 64; ++cc) {
    const float4* kp = (const float4*)(kT + (size_t)cc * 512 + lane * 8);
    float4 k0 = kp[0], k1 = kp[1];
    float kv[8] = {k0.x, k0.y, k0.z, k0.w, k1.x, k1.y, k1.z, k1.w};
    #pragma unroll
    for (int h = 0; h < 4; ++h) {
      float qv = qs[wid][h * 64 + cc];
      #pragma unroll
      for (int s = 0; s < 8; ++s) d[h][s] += qv * kv[s];
    }
  }
  float sc[8];
  #pragma unroll
  for (int s = 0; s < 8; ++s) {
    int n = lane * 8 + s;
    float v = wh[0] * fmaxf(d[0][s], 0.f) + wh[1] * fmaxf(d[1][s], 0.f)
            + wh[2] * fmaxf(d[2][s], 0.f) + wh[3] * fmaxf(d[3][s], 0.f);
    sc[s] = (n * 16 + 15 < t) ? v : -INFINITY;
  }
  float bv = -INFINITY; int bs = 0;
  #pragma unroll
  for (int s = 0; s < 8; ++s) if (sc[s] > bv) { bv = sc[s]; bs = s; }

  int* orow = top_idx + (size_t)t * 64;
  for (int j = 0; j < 64; ++j) {
    float v = bv; int n = lane * 8 + bs;
    #pragma unroll
    for (int off = 32; off >= 1; off >>= 1) {
      float ov = __shfl_xor(v, off);
      int   on = __shfl_xor(n, off);
      if (ov > v || (ov == v && on < n)) { v = ov; n = on; }
    }
    if (lane == 0) orow[j] = (v > -INFINITY) ? n : -1;
    if (v > -INFINITY && (n >> 3) == lane) {
      int rs = n & 7;
      #pragma unroll
      for (int s = 0; s < 8; ++s) sc[s] = (s == rs) ? -INFINITY : sc[s];
      bv = -INFINITY; bs = 0;
      #pragma unroll
      for (int s = 0; s < 8; ++s) if (sc[s] > bv) { bv = sc[s]; bs = s; }
    }
  }
}

// ---------------------------------------------------------------------------
// Sparse attention (q bf16, ckv f32 pre-normalized) -> attn bf16 (writes).
// Numerics bit-identical to the verified round-6 kernel.  Phases:
//  B) QK register-blocked 2 heads x 2 keys (round-11, validated)
//  C) row max pm[h] (16 threads, serial fmax — order-independent)
//  D) p = expf(sc - m) computed ONCE per (h,k), overwriting sc in place
//  E) PV with 256 threads (1 head x 8 d), l summed k-ascending as before
// ---------------------------------------------------------------------------
__global__ __launch_bounds__(256) void sparse_attn_k(
    const u16* __restrict__ q,       // (T, 16, 128) bf16
    const float* __restrict__ nckv,  // (512, 128)
    const int* __restrict__ top_idx, // (T, 64)
    u16* __restrict__ attn)          // (T, 16, 128) bf16
{
  int t = blockIdx.x;
  int tid = threadIdx.x;
  __shared__ float skv[64][132];
  __shared__ float qs[16][132];
  __shared__ float sc[16][65];
  __shared__ float pm[16];
  __shared__ int ivals[64];
  if (tid < 64) ivals[tid] = top_idx[(size_t)t * 64 + tid];
  __syncthreads();
  {
    int r = tid >> 2;
    int c0 = (tid & 3) * 32;
    int gi = ivals[r] >= 0 ? ivals[r] : 0;
    #pragma unroll
    for (int i = 0; i < 32; ++i)
      skv[r][c0 + i] = nckv[(size_t)gi * 128 + c0 + i];
  }
  for (int e = tid; e < 2048; e += 256)
    qs[e >> 7][e & 127] = b2f(q[(size_t)t * 2048 + e]);
  __syncthreads();
  // ---- B) QK: thread = (head pair h2, key kk) -> {2h2,2h2+1} x {kk,kk+32}
  {
    int h2 = tid >> 5;          // 0..7
    int kk = tid & 31;          // 0..31
    const float4* q0 = (const float4*)qs[2 * h2];
    const float4* q1 = (const float4*)qs[2 * h2 + 1];
    const float4* k0 = (const float4*)skv[kk];
    const float4* k1 = (const float4*)skv[kk + 32];
    float d00 = 0.f, d01 = 0.f, d10 = 0.f, d11 = 0.f;
    #pragma unroll
    for (int i = 0; i < 32; ++i) {
      float4 a0 = q0[i], a1 = q1[i], b0 = k0[i], b1 = k1[i];
      d00 += a0.x * b0.x + a0.y * b0.y + a0.z * b0.z + a0.w * b0.w;
      d01 += a0.x * b1.x + a0.y * b1.y + a0.z * b1.z + a0.w * b1.w;
      d10 += a1.x * b0.x + a1.y * b0.y + a1.z * b0.z + a1.w * b0.w;
      d11 += a1.x * b1.x + a1.y * b1.y + a1.z * b1.z + a1.w * b1.w;
    }
    bool v0 = ivals[kk] >= 0, v1 = ivals[kk + 32] >= 0;
    sc[2 * h2][kk]          = v0 ? d00 * SCALE : -INFINITY;
    sc[2 * h2][kk + 32]     = v1 ? d01 * SCALE : -INFINITY;
    sc[2 * h2 + 1][kk]      = v0 ? d10 * SCALE : -INFINITY;
    sc[2 * h2 + 1][kk + 32] = v1 ? d11 * SCALE : -INFINITY;
  }
  __syncthreads();
  // ---- C) row max (16 threads, k-ascending fmax as before)
  if (tid < 16) {
    float m = -INFINITY;
    for (int k = 0; k < 64; ++k) m = fmaxf(m, sc[tid][k]);
    pm[tid] = m;
  }
  __syncthreads();
  // ---- D) p = expf(sc - m) once per (h,k), in place
  {
    int h = tid >> 4;
    int k0 = (tid & 15) * 4;
    float m = pm[h];
    if (m > -INFINITY) {
      #pragma unroll
      for (int j = 0; j < 4; ++j)
        sc[h][k0 + j] = expf(sc[h][k0 + j] - m);
    }
  }
  __syncthreads();
  // ---- E) PV: thread = (head, 8-wide d slice); l summed k-ascending
  {
    int h = tid >> 4;
    int d0 = (tid & 15) * 8;
    float o[8] = {};
    if (pm[h] > -INFINITY) {
      float l = 0.f;
      for (int k = 0; k < 64; ++k) {
        float p = sc[h][k];
        l += p;
        const float4* vk = (const float4*)&skv[k][d0];
        float4 va = vk[0], vb = vk[1];
        o[0] += p * va.x; o[1] += p * va.y; o[2] += p * va.z; o[3] += p * va.w;
        o[4] += p * vb.x; o[5] += p * vb.y; o[6] += p * vb.z; o[7] += p * vb.w;
      }
      float inv = 1.0f / l;
      #pragma unroll
      for (int i = 0; i < 8; ++i) o[i] *= inv;
    }
    #pragma unroll
    for (int i = 0; i < 8; ++i)
      attn[(size_t)t * 2048 + h * 128 + d0 + i] = f2b(o[i]);
  }
}

// ---------------------------------------------------------------------------
// Sliding-window attention, bf16 MFMA flash.  Block = (64-q tile, head),
// 4 waves x 16 q-rows.  K swizzled in LDS, V transposed+padded, P via
// per-wave LDS.  attn (bf16) +=.
// ---------------------------------------------------------------------------
__global__ __launch_bounds__(256) void win_attn_mfma_k(
    const u16* __restrict__ q,     // (T, 16, 128) bf16
    const float* __restrict__ kv,  // (T, 512) f32: k@0, v@128
    u16* __restrict__ attn)        // (T, 16, 128) bf16 +=
{
  const int qt = blockIdx.x, hh = blockIdx.y;
  const int tid = threadIdx.x;
  const int wid = tid >> 6, lane = tid & 63;
  const int low = lane & 15, grp = lane >> 4;

  __shared__ __align__(16) u16 Ks[64 * 128];
  __shared__ __align__(16) u16 Vt[128 * 72];
  __shared__ __align__(16) u16 Pl[4][16 * 72];

  u16x8 qf[4];
  {
    const u16* qp = q + (size_t)(qt * 64 + wid * 16 + low) * 2048 + hh * 128 + grp * 8;
    #pragma unroll
    for (int kk = 0; kk < 4; ++kk) qf[kk] = *(const u16x8*)(qp + kk * 32);
  }
  f32x4 zero = {0.f, 0.f, 0.f, 0.f};
  f32x4 o[8];
  #pragma unroll
  for (int dt = 0; dt < 8; ++dt) o[dt] = zero;
  float mrow[4] = {-1e30f, -1e30f, -1e30f, -1e30f};
  float lrow[4] = {0.f, 0.f, 0.f, 0.f};

  const int kt0 = qt >= 4 ? qt - 4 : 0;
  const int srow = tid >> 2;
  const int scol = (tid & 3) * 32;
  for (int kt = kt0; kt <= qt; ++kt) {
    __syncthreads();
    {
      const float* gk = kv + (size_t)(kt * 64 + srow) * 512 + scol;
      u16 tmp[32];
      #pragma unroll
      for (int i = 0; i < 32; i += 4) {
        float4 v = *(const float4*)(gk + i);
        tmp[i] = f2b(v.x); tmp[i+1] = f2b(v.y); tmp[i+2] = f2b(v.z); tmp[i+3] = f2b(v.w);
      }
      #pragma unroll
      for (int j = 0; j < 4; ++j) {
        int c = scol + j * 8;
        *(u16x8*)(Ks + srow * 128 + (c ^ ((srow & 7) << 3))) = *(const u16x8*)(tmp + j * 8);
      }
      const float* gv = gk + 128;
      #pragma unroll
      for (int i = 0; i < 32; i += 4) {
        float4 v = *(const float4*)(gv + i);
        Vt[(scol + i + 0) * 72 + srow] = f2b(v.x);
        Vt[(scol + i + 1) * 72 + srow] = f2b(v.y);
        Vt[(scol + i + 2) * 72 + srow] = f2b(v.z);
        Vt[(scol + i + 3) * 72 + srow] = f2b(v.w);
      }
    }
    __syncthreads();
    f32x4 s[4];
    #pragma unroll
    for (int n = 0; n < 4; ++n) {
      s[n] = zero;
      int krow = n * 16 + low;
      #pragma unroll
      for (int kk = 0; kk < 4; ++kk) {
        u16x8 kf = *(const u16x8*)(Ks + krow * 128 + ((kk * 32 + grp * 8) ^ ((krow & 7) << 3)));
        mfma16(s[n], qf[kk], kf);
      }
    }
    asm volatile("s_nop 7\n\ts_nop 7");
    const int qg = qt * 64 + wid * 16 + grp * 4;
    #pragma unroll
    for (int n = 0; n < 4; ++n) {
      int kg = kt * 64 + n * 16 + low;
      #pragma unroll
      for (int r = 0; r < 4; ++r) {
        bool ok = (kg <= qg + r) && (kg > qg + r - 256);
        s[n][r] = ok ? s[n][r] * SCALE : -1e30f;
      }
    }
    float p[4][4];
    #pragma unroll
    for (int r = 0; r < 4; ++r) {
      float rm = fmaxf(fmaxf(s[0][r], s[1][r]), fmaxf(s[2][r], s[3][r]));
      rm = fmaxf(rm, __shfl_xor(rm, 1));
      rm = fmaxf(rm, __shfl_xor(rm, 2));
      rm = fmaxf(rm, __shfl_xor(rm, 4));
      rm = fmaxf(rm, __shfl_xor(rm, 8));
      float nm = fmaxf(mrow[r], rm);
      float f = __expf(mrow[r] - nm);
      mrow[r] = nm;
      float ps = 0.f;
      #pragma unroll
      for (int n = 0; n < 4; ++n) { p[n][r] = __expf(s[n][r] - nm); ps += p[n][r]; }
      ps += __shfl_xor(ps, 1); ps += __shfl_xor(ps, 2);
      ps += __shfl_xor(ps, 4); ps += __shfl_xor(ps, 8);
      lrow[r] = lrow[r] * f + ps;
      #pragma unroll
      for (int dt = 0; dt < 8; ++dt) o[dt][r] *= f;
    }
    u16* pw = Pl[wid];
    #pragma unroll
    for (int n = 0; n < 4; ++n)
      #pragma unroll
      for (int r = 0; r < 4; ++r)
        pw[(grp * 4 + r) * 72 + n * 16 + low] = f2b(p[n][r]);
    #pragma unroll
    for (int kk2 = 0; kk2 < 2; ++kk2) {
      u16x8 pa = *(const u16x8*)(pw + low * 72 + kk2 * 32 + grp * 8);
      #pragma unroll
      for (int dt = 0; dt < 8; ++dt) {
        u16x8 vf = *(const u16x8*)(Vt + (dt * 16 + low) * 72 + kk2 * 32 + grp * 8);
        mfma16(o[dt], pa, vf);
      }
    }
  }
  asm volatile("s_nop 7\n\ts_nop 7");
  float linv[4];
  #pragma unroll
  for (int r = 0; r < 4; ++r) linv[r] = 1.0f / lrow[r];
  u16* ap = attn + (size_t)(qt * 64 + wid * 16 + grp * 4) * 2048 + hh * 128 + low;
  #pragma unroll
  for (int r = 0; r < 4; ++r)
    #pragma unroll
    for (int dt = 0; dt < 8; ++dt) {
      size_t idx = (size_t)r * 2048 + dt * 16;
      ap[idx] = f2b(b2f(ap[idx]) + o[dt][r] * linv[r]);
    }
}

// ---------------------------------------------------------------------------
extern "C" void kernel_launch(void* const* d_in, const int* in_sizes, int n_in,
                              void* d_out, int out_size, void* d_ws, size_t ws_size,
                              hipStream_t stream)
{
  const float* h        = (const float*)d_in[0];
  const float* w_qc     = (const float*)d_in[1];
  const float* w_qup    = (const float*)d_in[2];
  const float* kvc_w    = (const float*)d_in[3];
  const float* kvc_wz   = (const float*)d_in[4];
  const float* kvc_bias = (const float*)d_in[5];
  const float* k_proj_w = (const float*)d_in[6];
  const float* v_proj_w = (const float*)d_in[7];
  const float* idx_c_w  = (const float*)d_in[8];
  const float* idx_c_wz = (const float*)d_in[9];
  const float* idx_c_bias = (const float*)d_in[10];
  const float* w_dq     = (const float*)d_in[11];
  const float* w_iuq    = (const float*)d_in[12];
  const float* w_w      = (const float*)d_in[13];
  const float* q_norm_w = (const float*)d_in[14];
  const float* k_norm_w = (const float*)d_in[15];
  const float* group_w  = (const float*)d_in[16];
  const float* final_w  = (const float*)d_in[17];
  float* out = (float*)d_out;

  float* ws = (float*)d_ws;
  size_t off = 0;
  auto alloc = [&](size_t nfloats) { float* p = ws + off; off += nfloats; return p; };
  float* cosT  = alloc((size_t)T_LEN * 32);
  float* sinT  = alloc((size_t)T_LEN * 32);
  u16* qb      = (u16*)alloc((size_t)T_LEN * 1024);
  u16* attnb   = (u16*)alloc((size_t)T_LEN * 1024);
  u16* hb      = (u16*)alloc((size_t)T_LEN * 1024);
  float* kvout = alloc((size_t)T_LEN * 512);
  float* ibuf  = alloc((size_t)T_LEN * 228);
  float* kT    = alloc((size_t)64 * NBLK);
  float* ckv   = alloc((size_t)NBLK * 128);
  float* qib   = alloc((size_t)T_LEN * 256);
  int*   topi  = (int*)alloc((size_t)T_LEN * 64);
  u16* w_qcT   = (u16*)alloc((size_t)512 * 1024);     // rows 0-511 of fused B
  u16* kvT     = (u16*)alloc((size_t)512 * 1024);     // rows 512-1023 (contiguous!)
  u16* w_qupT  = (u16*)alloc((size_t)2048 * 256);
  u16* gwT     = (u16*)alloc((size_t)4 * 512 * 256);
  u16* fwT     = (u16*)alloc((size_t)2048 * 1024);
  float* part  = alloc((size_t)4 * T_LEN * NIDX);     // split-K partials
  float* Bcat  = (float*)attnb;                       // 2048 x 196 f32
  u16* hq1b    = (u16*)((float*)attnb + 524288);
  u16* og      = qb;

  rope_cs_k<<<(T_LEN * 32 + 255) / 256, 256, 0, stream>>>(cosT, sinT);
  castk<<<(T_LEN * 2048 / 4 + 255) / 256, 256, 0, stream>>>(h, hb, T_LEN * 2048 / 4);
  tcast_k<<<dim3(16, 64), 256, 0, stream>>>(w_qc, w_qcT, 2048, 512);
  tcast_k<<<dim3(4, 64), 256, 0, stream>>>(k_proj_w, kvT + (size_t)0 * 128 * 2048, 2048, 128);
  tcast_k<<<dim3(4, 64), 256, 0, stream>>>(v_proj_w, kvT + (size_t)1 * 128 * 2048, 2048, 128);
  tcast_k<<<dim3(4, 64), 256, 0, stream>>>(kvc_w,    kvT + (size_t)2 * 128 * 2048, 2048, 128);
  tcast_k<<<dim3(4, 64), 256, 0, stream>>>(kvc_wz,   kvT + (size_t)3 * 128 * 2048, 2048, 128);
  tcast_k<<<dim3(64, 16), 256, 0, stream>>>(w_qup, w_qupT, 512, 2048);
  for (int g = 0; g < 4; ++g)
    tcast_k<<<dim3(16, 16), 256, 0, stream>>>(group_w + (size_t)g * 512 * 512,
                                              gwT + (size_t)g * 512 * 512, 512, 512);
  tcast_k<<<dim3(64, 64), 256, 0, stream>>>(final_w, fwT, 2048, 2048);
  concat_idx_k<<<(2048 * NIDX + 255) / 256, 256, 0, stream>>>(idx_c_w, idx_c_wz, w_dq, w_w, Bcat);

  // fused qc + k|v|kvc projections (one N=1024 bf16 MFMA GEMM, split outputs)
  bgemm_qckv_k<<<dim3(8, 64), 256, 0, stream>>>(hb, w_qcT, hq1b, kvout);

  // q chain tail
  bgemm_k<1><<<dim3(16, 64), 256, 0, stream>>>(hq1b, 512, w_qupT, 512, qb, 2048, 512);
  q_rope_norm_k<<<T_LEN * 4, 256, 0, stream>>>(qb, cosT, sinT, q_norm_w);

  // sliding-window k norm/rope + kv compression (normalize f32 rows in place)
  k_norm_rope_k<<<T_LEN / 4, 256, 0, stream>>>(kvout, cosT, sinT, k_norm_w);
  compress_k<<<(NBLK * 128 + 255) / 256, 256, 0, stream>>>(
      kvout + 256, kvout + 384, 512, kvc_bias, ckv, 128, 128, 1);
  rms_rows_k<<<NBLK / 4, 256, 0, stream>>>(ckv, k_norm_w);

  // index path (f32 exact for selection stability; split-K for occupancy)
  sgemm_splitk_k<<<dim3(4, 128, 4), 256, 0, stream>>>(h, HID, Bcat, NIDX, part, NIDX, T_LEN, NIDX, 512);
  reduce4_k<<<(T_LEN * NIDX + 255) / 256, 256, 0, stream>>>(part, NIDX, ibuf, 228, T_LEN);
  compress_k<<<(NBLK * 64 + 255) / 256, 256, 0, stream>>>(
      ibuf, ibuf + 64, 228, idx_c_bias, kT, 64, 1, NBLK);
  sgemm_k<<<dim3(4, 128), 256, 0, stream>>>(ibuf + 128, 228, w_iuq, 256, qib, 256, T_LEN, 256, 64);
  topk_k<<<T_LEN / 4, 256, 0, stream>>>(qib, ibuf + 192, 228, kT, topi);

  // attention
  sparse_attn_k<<<T_LEN, 256, 0, stream>>>(qb, ckv, topi, attnb);
  win_attn_mfma_k<<<dim3(T_LEN / 64, 16), 256, 0, stream>>>(qb, kvout, attnb);

  // output projections (bf16 MFMA): fused group projection, then final
  bgemm_group_k<<<dim3(4, 64, 4), 256, 0, stream>>>(attnb, gwT, og);
  bgemm_k<0><<<dim3(16, 64), 256, 0, stream>>>(og, 2048, fwT, 2048, out, 2048, 2048);
}

// Round 15
// 887.698 us; speedup vs baseline: 1.0554x; 1.0258x over previous
//
#include <hip/hip_runtime.h>
#include <math.h>

#define T_LEN 8192
#define HID   2048
#define NHEAD 16
#define HD    128
#define NBLK  512
#define NIDX  196                    // 64+64+64+4 used index-path columns
#define SCALE 0.08838834764831845f   // 1/sqrt(128)

typedef unsigned short u16;
typedef unsigned short u16x8 __attribute__((ext_vector_type(8)));
typedef float f32x4 __attribute__((ext_vector_type(4)));

// ---- bf16 <-> f32 via bit ops (RNE) ----
__device__ __forceinline__ u16 f2b(float f) {
  unsigned int u = __float_as_uint(f);
  return (u16)((u + 0x7fffu + ((u >> 16) & 1u)) >> 16);
}
__device__ __forceinline__ float b2f(u16 s) {
  return __uint_as_float(((unsigned int)s) << 16);
}

// ---- async global->LDS, 16B per lane (dest must be wave-linear) ----
__device__ __forceinline__ void gload16(const u16* g, u16* l) {
  __builtin_amdgcn_global_load_lds(
      (__attribute__((address_space(1))) void*)(uintptr_t)g,
      (__attribute__((address_space(3))) void*)(unsigned int)(uintptr_t)l,
      16, 0, 0);
}

// ---- MFMA 16x16x32 bf16 via inline asm (D/C tied) ----
__device__ __forceinline__ void mfma16(f32x4& d, u16x8 a, u16x8 b) {
  asm("v_mfma_f32_16x16x32_bf16 %0, %1, %2, %0" : "+v"(d) : "v"(a), "v"(b));
}

// ---------------------------------------------------------------------------
// bf16 MFMA GEMM: C[M,N] = A[M,K] @ Bt[N,K]^T.  m97 structure, 128x128 tile.
// ---------------------------------------------------------------------------
template<int OUT_BF16>
__global__ __launch_bounds__(256) void bgemm_k(
    const u16* __restrict__ A, int lda,
    const u16* __restrict__ Bt, int ldb,
    void* __restrict__ Cp, int ldc, int K)
{
  __shared__ __align__(16) u16 Al[128 * 32];
  __shared__ __align__(16) u16 Bl[128 * 32];
  const int tid = threadIdx.x;
  const int lane = tid & 63;
  const int bm = blockIdx.y * 128;
  const int bn = blockIdx.x * 128;
  const int wr = ((tid >> 6) >> 1) * 64;
  const int wc = ((tid >> 6) & 1) * 64;
  const int r0 = tid >> 2;
  const int c0 = (tid & 3) * 8;
  const u16* ga0 = A  + (size_t)(bm + r0) * lda + c0;
  const u16* ga1 = ga0 + (size_t)64 * lda;
  const u16* gb0 = Bt + (size_t)(bn + r0) * ldb + c0;
  const u16* gb1 = gb0 + (size_t)64 * ldb;
  u16* la0 = Al + tid * 8;
  u16* la1 = Al + (tid + 256) * 8;
  u16* lb0 = Bl + tid * 8;
  u16* lb1 = Bl + (tid + 256) * 8;

  f32x4 zero = {0.f, 0.f, 0.f, 0.f};
  f32x4 acc[4][4];
  #pragma unroll
  for (int m = 0; m < 4; ++m)
    #pragma unroll
    for (int n = 0; n < 4; ++n) acc[m][n] = zero;

  const int ar = wr + (lane & 15);
  const int br = wc + (lane & 15);
  const int ko = (lane >> 4) * 8;

  for (int k0 = 0; k0 < K; k0 += 32) {
    gload16(ga0 + k0, la0);
    gload16(ga1 + k0, la1);
    gload16(gb0 + k0, lb0);
    gload16(gb1 + k0, lb1);
    __syncthreads();
    u16x8 af[4], bfr[4];
    #pragma unroll
    for (int m = 0; m < 4; ++m)
      af[m] = *(const u16x8*)(Al + (size_t)(ar + m * 16) * 32 + ko);
    #pragma unroll
    for (int n = 0; n < 4; ++n)
      bfr[n] = *(const u16x8*)(Bl + (size_t)(br + n * 16) * 32 + ko);
    #pragma unroll
    for (int m = 0; m < 4; ++m)
      #pragma unroll
      for (int n = 0; n < 4; ++n) mfma16(acc[m][n], af[m], bfr[n]);
    __syncthreads();
  }
  asm volatile("s_nop 7\n\ts_nop 7");
  const int er = (lane >> 4) * 4;
  const int ec = lane & 15;
  #pragma unroll
  for (int m = 0; m < 4; ++m)
    #pragma unroll
    for (int n = 0; n < 4; ++n)
      #pragma unroll
      for (int r = 0; r < 4; ++r) {
        size_t idx = (size_t)(bm + wr + m * 16 + er + r) * ldc + (bn + wc + n * 16 + ec);
        if (OUT_BF16) ((u16*)Cp)[idx] = f2b(acc[m][n][r]);
        else          ((float*)Cp)[idx] = acc[m][n][r];
      }
}

// ---------------------------------------------------------------------------
// Fused qc|kv projection GEMM: A = hb (8192x2048), Bt = [w_qcT(512) ; kvT(512)]
// (1024x2048).  Cols 0-511 -> Cq bf16 (ld 512); cols 512-1023 -> Ckv f32 (ld 512).
// ---------------------------------------------------------------------------
__global__ __launch_bounds__(256) void bgemm_qckv_k(
    const u16* __restrict__ A, const u16* __restrict__ Bt,
    u16* __restrict__ Cq, float* __restrict__ Ckv)
{
  __shared__ __align__(16) u16 Al[128 * 32];
  __shared__ __align__(16) u16 Bl[128 * 32];
  const int tid = threadIdx.x;
  const int lane = tid & 63;
  const int bm = blockIdx.y * 128;
  const int bn = blockIdx.x * 128;
  const int wr = ((tid >> 6) >> 1) * 64;
  const int wc = ((tid >> 6) & 1) * 64;
  const int r0 = tid >> 2;
  const int c0 = (tid & 3) * 8;
  const u16* ga0 = A  + (size_t)(bm + r0) * 2048 + c0;
  const u16* ga1 = ga0 + (size_t)64 * 2048;
  const u16* gb0 = Bt + (size_t)(bn + r0) * 2048 + c0;
  const u16* gb1 = gb0 + (size_t)64 * 2048;
  u16* la0 = Al + tid * 8;
  u16* la1 = Al + (tid + 256) * 8;
  u16* lb0 = Bl + tid * 8;
  u16* lb1 = Bl + (tid + 256) * 8;

  f32x4 zero = {0.f, 0.f, 0.f, 0.f};
  f32x4 acc[4][4];
  #pragma unroll
  for (int m = 0; m < 4; ++m)
    #pragma unroll
    for (int n = 0; n < 4; ++n) acc[m][n] = zero;

  const int ar = wr + (lane & 15);
  const int br = wc + (lane & 15);
  const int ko = (lane >> 4) * 8;

  for (int k0 = 0; k0 < 2048; k0 += 32) {
    gload16(ga0 + k0, la0);
    gload16(ga1 + k0, la1);
    gload16(gb0 + k0, lb0);
    gload16(gb1 + k0, lb1);
    __syncthreads();
    u16x8 af[4], bfr[4];
    #pragma unroll
    for (int m = 0; m < 4; ++m)
      af[m] = *(const u16x8*)(Al + (size_t)(ar + m * 16) * 32 + ko);
    #pragma unroll
    for (int n = 0; n < 4; ++n)
      bfr[n] = *(const u16x8*)(Bl + (size_t)(br + n * 16) * 32 + ko);
    #pragma unroll
    for (int m = 0; m < 4; ++m)
      #pragma unroll
      for (int n = 0; n < 4; ++n) mfma16(acc[m][n], af[m], bfr[n]);
    __syncthreads();
  }
  asm volatile("s_nop 7\n\ts_nop 7");
  const int er = (lane >> 4) * 4;
  const int ec = lane & 15;
  if (bn < 512) {
    #pragma unroll
    for (int m = 0; m < 4; ++m)
      #pragma unroll
      for (int n = 0; n < 4; ++n)
        #pragma unroll
        for (int r = 0; r < 4; ++r)
          Cq[(size_t)(bm + wr + m * 16 + er + r) * 512 + (bn + wc + n * 16 + ec)]
              = f2b(acc[m][n][r]);
  } else {
    #pragma unroll
    for (int m = 0; m < 4; ++m)
      #pragma unroll
      for (int n = 0; n < 4; ++n)
        #pragma unroll
        for (int r = 0; r < 4; ++r)
          Ckv[(size_t)(bm + wr + m * 16 + er + r) * 512 + (bn - 512 + wc + n * 16 + ec)]
              = acc[m][n][r];
  }
}

// ---------------------------------------------------------------------------
// Fused group projection: z = group.  A = attnb + z*512 (ld 2048), K=512,
// Bt = gwT + z*512*512, C = og + z*512 (ld 2048) bf16.
// ---------------------------------------------------------------------------
__global__ __launch_bounds__(256) void bgemm_group_k(
    const u16* __restrict__ Ab, const u16* __restrict__ gw,
    u16* __restrict__ Cb)
{
  __shared__ __align__(16) u16 Al[128 * 32];
  __shared__ __align__(16) u16 Bl[128 * 32];
  const int tid = threadIdx.x;
  const int lane = tid & 63;
  const int bm = blockIdx.y * 128;
  const int bn = blockIdx.x * 128;
  const int g  = blockIdx.z;
  const u16* A  = Ab + (size_t)g * 512;
  const u16* Bt = gw + (size_t)g * 512 * 512;
  u16* C = Cb + (size_t)g * 512;
  const int wr = ((tid >> 6) >> 1) * 64;
  const int wc = ((tid >> 6) & 1) * 64;
  const int r0 = tid >> 2;
  const int c0 = (tid & 3) * 8;
  const u16* ga0 = A  + (size_t)(bm + r0) * 2048 + c0;
  const u16* ga1 = ga0 + (size_t)64 * 2048;
  const u16* gb0 = Bt + (size_t)(bn + r0) * 512 + c0;
  const u16* gb1 = gb0 + (size_t)64 * 512;
  u16* la0 = Al + tid * 8;
  u16* la1 = Al + (tid + 256) * 8;
  u16* lb0 = Bl + tid * 8;
  u16* lb1 = Bl + (tid + 256) * 8;

  f32x4 zero = {0.f, 0.f, 0.f, 0.f};
  f32x4 acc[4][4];
  #pragma unroll
  for (int m = 0; m < 4; ++m)
    #pragma unroll
    for (int n = 0; n < 4; ++n) acc[m][n] = zero;

  const int ar = wr + (lane & 15);
  const int br = wc + (lane & 15);
  const int ko = (lane >> 4) * 8;

  for (int k0 = 0; k0 < 512; k0 += 32) {
    gload16(ga0 + k0, la0);
    gload16(ga1 + k0, la1);
    gload16(gb0 + k0, lb0);
    gload16(gb1 + k0, lb1);
    __syncthreads();
    u16x8 af[4], bfr[4];
    #pragma unroll
    for (int m = 0; m < 4; ++m)
      af[m] = *(const u16x8*)(Al + (size_t)(ar + m * 16) * 32 + ko);
    #pragma unroll
    for (int n = 0; n < 4; ++n)
      bfr[n] = *(const u16x8*)(Bl + (size_t)(br + n * 16) * 32 + ko);
    #pragma unroll
    for (int m = 0; m < 4; ++m)
      #pragma unroll
      for (int n = 0; n < 4; ++n) mfma16(acc[m][n], af[m], bfr[n]);
    __syncthreads();
  }
  asm volatile("s_nop 7\n\ts_nop 7");
  const int er = (lane >> 4) * 4;
  const int ec = lane & 15;
  #pragma unroll
  for (int m = 0; m < 4; ++m)
    #pragma unroll
    for (int n = 0; n < 4; ++n)
      #pragma unroll
      for (int r = 0; r < 4; ++r)
        C[(size_t)(bm + wr + m * 16 + er + r) * 2048 + (bn + wc + n * 16 + ec)]
            = f2b(acc[m][n][r]);
}

// ---------------------------------------------------------------------------
// f32 GEMM with split-K, 64x64 tile, 4x4 micro-tile, BK=16 (round-12
// verified: 183 us).  blockIdx.z selects K-chunk; partials P[z][M][ldc].
// ---------------------------------------------------------------------------
__global__ __launch_bounds__(256) void sgemm_splitk_k(
    const float* __restrict__ A, int lda,
    const float* __restrict__ B, int ldb,
    float* __restrict__ P, int ldc,
    int M, int N, int kchunk)
{
  __shared__ __align__(16) float As[16][68];
  __shared__ __align__(16) float Bs[16][68];
  const int bm = blockIdx.y * 64;
  const int bn = blockIdx.x * 64;
  const int kb = blockIdx.z * kchunk;
  float* C = P + (size_t)blockIdx.z * M * ldc;
  const int tid = threadIdx.x;
  const int tx = tid & 15;
  const int ty = tid >> 4;
  float acc[4][4] = {};
  for (int k0 = 0; k0 < kchunk; k0 += 16) {
    #pragma unroll
    for (int i = 0; i < 4; ++i) {
      int f = tid + i * 256;
      int r = f >> 4, c = f & 15;
      float v = 0.f;
      int gr = bm + r, gc = kb + k0 + c;
      if (gr < M) v = A[(size_t)gr * lda + gc];
      As[c][r] = v;
    }
    #pragma unroll
    for (int i = 0; i < 4; ++i) {
      int f = tid + i * 256;
      int r = f >> 6, c = f & 63;
      float v = 0.f;
      int gr = kb + k0 + r, gc = bn + c;
      if (gc < N) v = B[(size_t)gr * ldb + gc];
      Bs[r][c] = v;
    }
    __syncthreads();
    #pragma unroll
    for (int kk = 0; kk < 16; ++kk) {
      float4 a = *(const float4*)&As[kk][ty * 4];
      float4 b = *(const float4*)&Bs[kk][tx * 4];
      float av[4] = {a.x, a.y, a.z, a.w};
      float bv[4] = {b.x, b.y, b.z, b.w};
      #pragma unroll
      for (int i = 0; i < 4; ++i)
        #pragma unroll
        for (int j = 0; j < 4; ++j) acc[i][j] += av[i] * bv[j];
    }
    __syncthreads();
  }
  #pragma unroll
  for (int i = 0; i < 4; ++i) {
    int gr = bm + ty * 4 + i;
    if (gr >= M) continue;
    #pragma unroll
    for (int j = 0; j < 4; ++j) {
      int gc = bn + tx * 4 + j;
      if (gc < N) C[(size_t)gr * ldc + gc] = acc[i][j];
    }
  }
}

// ---- sum 4 split-K partials [4][M][ldp] -> out[M][ldo] ----
__global__ void reduce4_k(const float* __restrict__ P, int ldp,
                          float* __restrict__ o, int ldo, int M)
{
  int i = blockIdx.x * 256 + threadIdx.x;
  if (i >= M * ldp) return;
  int r = i / ldp, c = i % ldp;
  size_t st = (size_t)M * ldp;
  float v = P[i] + P[i + st] + P[i + 2 * st] + P[i + 3 * st];
  o[(size_t)r * ldo + c] = v;
}

// ---------------------------------------------------------------------------
// Generic tiled f32 GEMM (small-K qib GEMM), vectorized LDS reads.
// ---------------------------------------------------------------------------
__global__ __launch_bounds__(256) void sgemm_k(
    const float* __restrict__ A, int lda,
    const float* __restrict__ B, int ldb,
    float* __restrict__ C, int ldc,
    int M, int N, int K)
{
  __shared__ __align__(16) float As[16][68];
  __shared__ __align__(16) float Bs[16][68];
  const int bm = blockIdx.y * 64;
  const int bn = blockIdx.x * 64;
  const int tid = threadIdx.x;
  const int tx = tid & 15;
  const int ty = tid >> 4;
  float acc[4][4] = {};
  for (int k0 = 0; k0 < K; k0 += 16) {
    #pragma unroll
    for (int i = 0; i < 4; ++i) {
      int f = tid + i * 256;
      int r = f >> 4, c = f & 15;
      float v = 0.f;
      int gr = bm + r, gc = k0 + c;
      if (gr < M && gc < K) v = A[(size_t)gr * lda + gc];
      As[c][r] = v;
    }
    #pragma unroll
    for (int i = 0; i < 4; ++i) {
      int f = tid + i * 256;
      int r = f >> 6, c = f & 63;
      float v = 0.f;
      int gr = k0 + r, gc = bn + c;
      if (gr < K && gc < N) v = B[(size_t)gr * ldb + gc];
      Bs[r][c] = v;
    }
    __syncthreads();
    #pragma unroll
    for (int kk = 0; kk < 16; ++kk) {
      float4 a = *(const float4*)&As[kk][ty * 4];
      float4 b = *(const float4*)&Bs[kk][tx * 4];
      float av[4] = {a.x, a.y, a.z, a.w};
      float bv[4] = {b.x, b.y, b.z, b.w};
      #pragma unroll
      for (int i = 0; i < 4; ++i)
        #pragma unroll
        for (int j = 0; j < 4; ++j) acc[i][j] += av[i] * bv[j];
    }
    __syncthreads();
  }
  #pragma unroll
  for (int i = 0; i < 4; ++i) {
    int gr = bm + ty * 4 + i;
    if (gr >= M) continue;
    #pragma unroll
    for (int j = 0; j < 4; ++j) {
      int gc = bn + tx * 4 + j;
      if (gc < N) C[(size_t)gr * ldc + gc] = acc[i][j];
    }
  }
}

// ---------------------------------------------------------------------------
// f32 -> bf16 cast (4 elems/thread)
// ---------------------------------------------------------------------------
__global__ void castk(const float* __restrict__ in, u16* __restrict__ out, int n4)
{
  int i = blockIdx.x * 256 + threadIdx.x;
  if (i >= n4) return;
  float4 v = ((const float4*)in)[i];
  unsigned int lo = (unsigned int)f2b(v.x) | ((unsigned int)f2b(v.y) << 16);
  unsigned int hi = (unsigned int)f2b(v.z) | ((unsigned int)f2b(v.w) << 16);
  ((uint2*)out)[i] = make_uint2(lo, hi);
}

// ---------------------------------------------------------------------------
// transpose + cast: in f32 [R][C] -> out bf16 [C][R]
// ---------------------------------------------------------------------------
__global__ __launch_bounds__(256) void tcast_k(
    const float* __restrict__ in, u16* __restrict__ outT, int R, int C)
{
  __shared__ float t[32][33];
  int bc = blockIdx.x * 32, br = blockIdx.y * 32;
  int lx = threadIdx.x & 31, ly = threadIdx.x >> 5;
  #pragma unroll
  for (int i = 0; i < 32; i += 8) {
    int r = br + ly + i, c = bc + lx;
    t[ly + i][lx] = (r < R && c < C) ? in[(size_t)r * C + c] : 0.f;
  }
  __syncthreads();
  #pragma unroll
  for (int i = 0; i < 32; i += 8) {
    int c = bc + ly + i, r = br + lx;
    if (c < C && r < R) outT[(size_t)c * R + r] = f2b(t[lx][ly + i]);
  }
}

// ---------------------------------------------------------------------------
// Concat the 4 index-path weights into Bcat f32 (2048 x 196)
// ---------------------------------------------------------------------------
__global__ void concat_idx_k(const float* __restrict__ a, const float* __restrict__ b,
                             const float* __restrict__ c, const float* __restrict__ d,
                             float* __restrict__ o)
{
  int i = blockIdx.x * 256 + threadIdx.x;
  if (i >= 2048 * NIDX) return;
  int r = i / NIDX, col = i % NIDX;
  float v = (col < 64)  ? a[r * 64 + col]
          : (col < 128) ? b[r * 64 + col - 64]
          : (col < 192) ? c[r * 64 + col - 128]
          :               d[r * 4 + col - 192];
  o[i] = v;
}

// ---------------------------------------------------------------------------
// RoPE cos/sin tables: (T, 32) each.
// ---------------------------------------------------------------------------
__global__ void rope_cs_k(float* __restrict__ ct, float* __restrict__ st)
{
  int idx = blockIdx.x * blockDim.x + threadIdx.x;
  if (idx >= T_LEN * 32) return;
  int t = idx >> 5, i = idx & 31;
  float inv = powf(10000.0f, -(float)(2 * i) / 64.0f);
  float ang = (float)t * inv;
  ct[idx] = cosf(ang);
  st[idx] = sinf(ang);
}

// ---------------------------------------------------------------------------
// q (bf16, row = t*16+h): rope then rmsnorm, in place. 4 rows/block (1/wave).
// ---------------------------------------------------------------------------
__global__ __launch_bounds__(256) void q_rope_norm_k(
    u16* __restrict__ q, const float* __restrict__ ct,
    const float* __restrict__ st, const float* __restrict__ w)
{
  int wid = threadIdx.x >> 6;
  int row = blockIdx.x * 4 + wid;
  int t = row >> 4;
  int lane = threadIdx.x & 63;
  __shared__ float ls[4][128];
  u16* rp = q + (size_t)row * 128;
  ls[wid][lane] = b2f(rp[lane]);
  ls[wid][lane + 64] = b2f(rp[lane + 64]);
  __syncthreads();
  float v0;
  if (lane < 32) {
    float c = ct[t * 32 + lane], s = st[t * 32 + lane];
    v0 = ls[wid][lane] * c - ls[wid][lane + 32] * s;
  } else {
    int i = lane - 32;
    float c = ct[t * 32 + i], s = st[t * 32 + i];
    v0 = ls[wid][i] * s + ls[wid][lane] * c;
  }
  float v1 = ls[wid][lane + 64];
  float ss = v0 * v0 + v1 * v1;
  #pragma unroll
  for (int off = 1; off < 64; off <<= 1) ss += __shfl_xor(ss, off);
  float rn = 1.0f / sqrtf(ss / 128.0f + 1e-6f);
  rp[lane] = f2b(v0 * rn * w[lane]);
  rp[lane + 64] = f2b(v1 * rn * w[lane + 64]);
}

// ---------------------------------------------------------------------------
// sw_k inside kvout (f32, row stride 512, cols 0..127): rmsnorm then rope.
// ---------------------------------------------------------------------------
__global__ __launch_bounds__(256) void k_norm_rope_k(
    float* __restrict__ kv, const float* __restrict__ ct,
    const float* __restrict__ st, const float* __restrict__ w)
{
  int wid = threadIdx.x >> 6;
  int t = blockIdx.x * 4 + wid;
  int lane = threadIdx.x & 63;
  __shared__ float ls[4][128];
  float* rp = kv + (size_t)t * 512;
  float a = rp[lane], b = rp[lane + 64];
  float ss = a * a + b * b;
  #pragma unroll
  for (int off = 1; off < 64; off <<= 1) ss += __shfl_xor(ss, off);
  float rn = 1.0f / sqrtf(ss / 128.0f + 1e-6f);
  a *= rn * w[lane];
  b *= rn * w[lane + 64];
  ls[wid][lane] = a;
  ls[wid][lane + 64] = b;
  __syncthreads();
  float v0;
  if (lane < 32) {
    float c = ct[t * 32 + lane], s = st[t * 32 + lane];
    v0 = ls[wid][lane] * c - ls[wid][lane + 32] * s;
  } else {
    int i = lane - 32;
    float c = ct[t * 32 + i], s = st[t * 32 + i];
    v0 = ls[wid][i] * s + ls[wid][lane] * c;
  }
  rp[lane] = v0;
  rp[lane + 64] = b;
}

// ---------------------------------------------------------------------------
// rmsnorm 128-wide f32 rows in place.  4 rows per block (1/wave).
// ---------------------------------------------------------------------------
__global__ __launch_bounds__(256) void rms_rows_k(
    float* __restrict__ x, const float* __restrict__ w)
{
  int r = blockIdx.x * 4 + (threadIdx.x >> 6);
  int lane = threadIdx.x & 63;
  float* rp = x + (size_t)r * 128;
  float a = rp[lane], b = rp[lane + 64];
  float ss = a * a + b * b;
  #pragma unroll
  for (int off = 1; off < 64; off <<= 1) ss += __shfl_xor(ss, off);
  float rn = 1.0f / sqrtf(ss / 128.0f + 1e-6f);
  rp[lane] = a * rn * w[lane];
  rp[lane + 64] = b * rn * w[lane + 64];
}

// ---------------------------------------------------------------------------
// compress with input row-stride ldin: out[n*sn + d*sd]
// ---------------------------------------------------------------------------
__global__ void compress_k(
    const float* __restrict__ c, const float* __restrict__ z, int ldin,
    const float* __restrict__ bias, float* __restrict__ out,
    int D, int sn, int sd)
{
  int idx = blockIdx.x * blockDim.x + threadIdx.x;
  if (idx >= NBLK * D) return;
  int n = idx / D, d = idx % D;
  float zb[16];
  float mx = -INFINITY;
  #pragma unroll
  for (int m = 0; m < 16; ++m) {
    float v = z[(size_t)(n * 16 + m) * ldin + d] + bias[m * D + d];
    zb[m] = v;
    mx = fmaxf(mx, v);
  }
  float s = 0.f;
  #pragma unroll
  for (int m = 0; m < 16; ++m) { zb[m] = expf(zb[m] - mx); s += zb[m]; }
  float acc = 0.f;
  #pragma unroll
  for (int m = 0; m < 16; ++m) acc += zb[m] * c[(size_t)(n * 16 + m) * ldin + d];
  out[(size_t)n * sn + (size_t)d * sd] = acc / s;
}

// ---------------------------------------------------------------------------
// Top-64 per t, fully in-register, one wave per t (4 waves/block).
// ---------------------------------------------------------------------------
__global__ __launch_bounds__(256) void topk_k(
    const float* __restrict__ qi,    // (T, 4, 64)
    const float* __restrict__ wih, int wst,
    const float* __restrict__ kT,    // (64, 512)
    int* __restrict__ top_idx)       // (T, 64)
{
  const int wid = threadIdx.x >> 6;
  const int lane = threadIdx.x & 63;
  const int t = blockIdx.x * 4 + wid;
  __shared__ float qs[4][256];
  for (int i = lane; i < 256; i += 64) qs[wid][i] = qi[(size_t)t * 256 + i];
  float wh[4];
  #pragma unroll
  for (int h = 0; h < 4; ++h) wh[h] = wih[(size_t)t * wst + h];
  __syncthreads();

  float d[4][8] = {};
  for (int cc = 0; cc < 64; ++cc) {
    const float4* kp = (const float4*)(kT + (size_t)cc * 512 + lane * 8);
    float4 k0 = kp[0], k1 = kp[1];
    float kv[8] = {k0.x, k0.y, k0.z, k0.w, k1.x, k1.y, k1.z, k1.w};
    #pragma unroll
    for (int h = 0; h < 4; ++h) {
      float qv = qs[wid][h * 64 + cc];
      #pragma unroll
      for (int s = 0; s < 8; ++s) d[h][s] += qv * kv[s];
    }
  }
  float sc[8];
  #pragma unroll
  for (int s = 0; s < 8; ++s) {
    int n = lane * 8 + s;
    float v = wh[0] * fmaxf(d[0][s], 0.f) + wh[1] * fmaxf(d[1][s], 0.f)
            + wh[2] * fmaxf(d[2][s], 0.f) + wh[3] * fmaxf(d[3][s], 0.f);
    sc[s] = (n * 16 + 15 < t) ? v : -INFINITY;
  }
  float bv = -INFINITY; int bs = 0;
  #pragma unroll
  for (int s = 0; s < 8; ++s) if (sc[s] > bv) { bv = sc[s]; bs = s; }

  int* orow = top_idx + (size_t)t * 64;
  for (int j = 0; j < 64; ++j) {
    float v = bv; int n = lane * 8 + bs;
    #pragma unroll
    for (int off = 32; off >= 1; off >>= 1) {
      float ov = __shfl_xor(v, off);
      int   on = __shfl_xor(n, off);
      if (ov > v || (ov == v && on < n)) { v = ov; n = on; }
    }
    if (lane == 0) orow[j] = (v > -INFINITY) ? n : -1;
    if (v > -INFINITY && (n >> 3) == lane) {
      int rs = n & 7;
      #pragma unroll
      for (int s = 0; s < 8; ++s) sc[s] = (s == rs) ? -INFINITY : sc[s];
      bv = -INFINITY; bs = 0;
      #pragma unroll
      for (int s = 0; s < 8; ++s) if (sc[s] > bv) { bv = sc[s]; bs = s; }
    }
  }
}

// ---------------------------------------------------------------------------
// Sparse attention (q bf16, ckv f32 pre-normalized) -> attn bf16 (writes).
// Numerics bit-identical to the verified round-6 kernel.  Phases:
//  B) QK register-blocked 2 heads x 2 keys (round-11, validated)
//  C) row max pm[h] (16 threads, serial fmax — order-independent)
//  D) p = expf(sc - m) computed ONCE per (h,k), overwriting sc in place
//  E) PV with 256 threads (1 head x 8 d), l summed k-ascending as before
// ---------------------------------------------------------------------------
__global__ __launch_bounds__(256) void sparse_attn_k(
    const u16* __restrict__ q,       // (T, 16, 128) bf16
    const float* __restrict__ nckv,  // (512, 128)
    const int* __restrict__ top_idx, // (T, 64)
    u16* __restrict__ attn)          // (T, 16, 128) bf16
{
  int t = blockIdx.x;
  int tid = threadIdx.x;
  __shared__ float skv[64][132];
  __shared__ float qs[16][132];
  __shared__ float sc[16][65];
  __shared__ float pm[16];
  __shared__ int ivals[64];
  if (tid < 64) ivals[tid] = top_idx[(size_t)t * 64 + tid];
  __syncthreads();
  {
    int r = tid >> 2;
    int c0 = (tid & 3) * 32;
    int gi = ivals[r] >= 0 ? ivals[r] : 0;
    #pragma unroll
    for (int i = 0; i < 32; ++i)
      skv[r][c0 + i] = nckv[(size_t)gi * 128 + c0 + i];
  }
  for (int e = tid; e < 2048; e += 256)
    qs[e >> 7][e & 127] = b2f(q[(size_t)t * 2048 + e]);
  __syncthreads();
  // ---- B) QK: thread = (head pair h2, key kk) -> {2h2,2h2+1} x {kk,kk+32}
  {
    int h2 = tid >> 5;          // 0..7
    int kk = tid & 31;          // 0..31
    const float4* q0 = (const float4*)qs[2 * h2];
    const float4* q1 = (const float4*)qs[2 * h2 + 1];
    const float4* k0 = (const float4*)skv[kk];
    const float4* k1 = (const float4*)skv[kk + 32];
    float d00 = 0.f, d01 = 0.f, d10 = 0.f, d11 = 0.f;
    #pragma unroll
    for (int i = 0; i < 32; ++i) {
      float4 a0 = q0[i], a1 = q1[i], b0 = k0[i], b1 = k1[i];
      d00 += a0.x * b0.x + a0.y * b0.y + a0.z * b0.z + a0.w * b0.w;
      d01 += a0.x * b1.x + a0.y * b1.y + a0.z * b1.z + a0.w * b1.w;
      d10 += a1.x * b0.x + a1.y * b0.y + a1.z * b0.z + a1.w * b0.w;
      d11 += a1.x * b1.x + a1.y * b1.y + a1.z * b1.z + a1.w * b1.w;
    }
    bool v0 = ivals[kk] >= 0, v1 = ivals[kk + 32] >= 0;
    sc[2 * h2][kk]          = v0 ? d00 * SCALE : -INFINITY;
    sc[2 * h2][kk + 32]     = v1 ? d01 * SCALE : -INFINITY;
    sc[2 * h2 + 1][kk]      = v0 ? d10 * SCALE : -INFINITY;
    sc[2 * h2 + 1][kk + 32] = v1 ? d11 * SCALE : -INFINITY;
  }
  __syncthreads();
  // ---- C) row max (16 threads, k-ascending fmax as before)
  if (tid < 16) {
    float m = -INFINITY;
    for (int k = 0; k < 64; ++k) m = fmaxf(m, sc[tid][k]);
    pm[tid] = m;
  }
  __syncthreads();
  // ---- D) p = expf(sc - m) once per (h,k), in place
  {
    int h = tid >> 4;
    int k0 = (tid & 15) * 4;
    float m = pm[h];
    if (m > -INFINITY) {
      #pragma unroll
      for (int j = 0; j < 4; ++j)
        sc[h][k0 + j] = expf(sc[h][k0 + j] - m);
    }
  }
  __syncthreads();
  // ---- E) PV: thread = (head, 8-wide d slice); l summed k-ascending
  {
    int h = tid >> 4;
    int d0 = (tid & 15) * 8;
    float o[8] = {};
    if (pm[h] > -INFINITY) {
      float l = 0.f;
      for (int k = 0; k < 64; ++k) {
        float p = sc[h][k];
        l += p;
        const float4* vk = (const float4*)&skv[k][d0];
        float4 va = vk[0], vb = vk[1];
        o[0] += p * va.x; o[1] += p * va.y; o[2] += p * va.z; o[3] += p * va.w;
        o[4] += p * vb.x; o[5] += p * vb.y; o[6] += p * vb.z; o[7] += p * vb.w;
      }
      float inv = 1.0f / l;
      #pragma unroll
      for (int i = 0; i < 8; ++i) o[i] *= inv;
    }
    #pragma unroll
    for (int i = 0; i < 8; ++i)
      attn[(size_t)t * 2048 + h * 128 + d0 + i] = f2b(o[i]);
  }
}

// ---------------------------------------------------------------------------
// Sliding-window attention, bf16 MFMA flash.  Block = (64-q tile, head),
// 4 waves x 16 q-rows.  K swizzled in LDS, V transposed+padded, P via
// per-wave LDS.  attn (bf16) +=.
// ---------------------------------------------------------------------------
__global__ __launch_bounds__(256) void win_attn_mfma_k(
    const u16* __restrict__ q,     // (T, 16, 128) bf16
    const float* __restrict__ kv,  // (T, 512) f32: k@0, v@128
    u16* __restrict__ attn)        // (T, 16, 128) bf16 +=
{
  const int qt = blockIdx.x, hh = blockIdx.y;
  const int tid = threadIdx.x;
  const int wid = tid >> 6, lane = tid & 63;
  const int low = lane & 15, grp = lane >> 4;

  __shared__ __align__(16) u16 Ks[64 * 128];
  __shared__ __align__(16) u16 Vt[128 * 72];
  __shared__ __align__(16) u16 Pl[4][16 * 72];

  u16x8 qf[4];
  {
    const u16* qp = q + (size_t)(qt * 64 + wid * 16 + low) * 2048 + hh * 128 + grp * 8;
    #pragma unroll
    for (int kk = 0; kk < 4; ++kk) qf[kk] = *(const u16x8*)(qp + kk * 32);
  }
  f32x4 zero = {0.f, 0.f, 0.f, 0.f};
  f32x4 o[8];
  #pragma unroll
  for (int dt = 0; dt < 8; ++dt) o[dt] = zero;
  float mrow[4] = {-1e30f, -1e30f, -1e30f, -1e30f};
  float lrow[4] = {0.f, 0.f, 0.f, 0.f};

  const int kt0 = qt >= 4 ? qt - 4 : 0;
  const int srow = tid >> 2;
  const int scol = (tid & 3) * 32;
  for (int kt = kt0; kt <= qt; ++kt) {
    __syncthreads();
    {
      const float* gk = kv + (size_t)(kt * 64 + srow) * 512 + scol;
      u16 tmp[32];
      #pragma unroll
      for (int i = 0; i < 32; i += 4) {
        float4 v = *(const float4*)(gk + i);
        tmp[i] = f2b(v.x); tmp[i+1] = f2b(v.y); tmp[i+2] = f2b(v.z); tmp[i+3] = f2b(v.w);
      }
      #pragma unroll
      for (int j = 0; j < 4; ++j) {
        int c = scol + j * 8;
        *(u16x8*)(Ks + srow * 128 + (c ^ ((srow & 7) << 3))) = *(const u16x8*)(tmp + j * 8);
      }
      const float* gv = gk + 128;
      #pragma unroll
      for (int i = 0; i < 32; i += 4) {
        float4 v = *(const float4*)(gv + i);
        Vt[(scol + i + 0) * 72 + srow] = f2b(v.x);
        Vt[(scol + i + 1) * 72 + srow] = f2b(v.y);
        Vt[(scol + i + 2) * 72 + srow] = f2b(v.z);
        Vt[(scol + i + 3) * 72 + srow] = f2b(v.w);
      }
    }
    __syncthreads();
    f32x4 s[4];
    #pragma unroll
    for (int n = 0; n < 4; ++n) {
      s[n] = zero;
      int krow = n * 16 + low;
      #pragma unroll
      for (int kk = 0; kk < 4; ++kk) {
        u16x8 kf = *(const u16x8*)(Ks + krow * 128 + ((kk * 32 + grp * 8) ^ ((krow & 7) << 3)));
        mfma16(s[n], qf[kk], kf);
      }
    }
    asm volatile("s_nop 7\n\ts_nop 7");
    const int qg = qt * 64 + wid * 16 + grp * 4;
    #pragma unroll
    for (int n = 0; n < 4; ++n) {
      int kg = kt * 64 + n * 16 + low;
      #pragma unroll
      for (int r = 0; r < 4; ++r) {
        bool ok = (kg <= qg + r) && (kg > qg + r - 256);
        s[n][r] = ok ? s[n][r] * SCALE : -1e30f;
      }
    }
    float p[4][4];
    #pragma unroll
    for (int r = 0; r < 4; ++r) {
      float rm = fmaxf(fmaxf(s[0][r], s[1][r]), fmaxf(s[2][r], s[3][r]));
      rm = fmaxf(rm, __shfl_xor(rm, 1));
      rm = fmaxf(rm, __shfl_xor(rm, 2));
      rm = fmaxf(rm, __shfl_xor(rm, 4));
      rm = fmaxf(rm, __shfl_xor(rm, 8));
      float nm = fmaxf(mrow[r], rm);
      float f = __expf(mrow[r] - nm);
      mrow[r] = nm;
      float ps = 0.f;
      #pragma unroll
      for (int n = 0; n < 4; ++n) { p[n][r] = __expf(s[n][r] - nm); ps += p[n][r]; }
      ps += __shfl_xor(ps, 1); ps += __shfl_xor(ps, 2);
      ps += __shfl_xor(ps, 4); ps += __shfl_xor(ps, 8);
      lrow[r] = lrow[r] * f + ps;
      #pragma unroll
      for (int dt = 0; dt < 8; ++dt) o[dt][r] *= f;
    }
    u16* pw = Pl[wid];
    #pragma unroll
    for (int n = 0; n < 4; ++n)
      #pragma unroll
      for (int r = 0; r < 4; ++r)
        pw[(grp * 4 + r) * 72 + n * 16 + low] = f2b(p[n][r]);
    #pragma unroll
    for (int kk2 = 0; kk2 < 2; ++kk2) {
      u16x8 pa = *(const u16x8*)(pw + low * 72 + kk2 * 32 + grp * 8);
      #pragma unroll
      for (int dt = 0; dt < 8; ++dt) {
        u16x8 vf = *(const u16x8*)(Vt + (dt * 16 + low) * 72 + kk2 * 32 + grp * 8);
        mfma16(o[dt], pa, vf);
      }
    }
  }
  asm volatile("s_nop 7\n\ts_nop 7");
  float linv[4];
  #pragma unroll
  for (int r = 0; r < 4; ++r) linv[r] = 1.0f / lrow[r];
  u16* ap = attn + (size_t)(qt * 64 + wid * 16 + grp * 4) * 2048 + hh * 128 + low;
  #pragma unroll
  for (int r = 0; r < 4; ++r)
    #pragma unroll
    for (int dt = 0; dt < 8; ++dt) {
      size_t idx = (size_t)r * 2048 + dt * 16;
      ap[idx] = f2b(b2f(ap[idx]) + o[dt][r] * linv[r]);
    }
}

// ---------------------------------------------------------------------------
extern "C" void kernel_launch(void* const* d_in, const int* in_sizes, int n_in,
                              void* d_out, int out_size, void* d_ws, size_t ws_size,
                              hipStream_t stream)
{
  const float* h        = (const float*)d_in[0];
  const float* w_qc     = (const float*)d_in[1];
  const float* w_qup    = (const float*)d_in[2];
  const float* kvc_w    = (const float*)d_in[3];
  const float* kvc_wz   = (const float*)d_in[4];
  const float* kvc_bias = (const float*)d_in[5];
  const float* k_proj_w = (const float*)d_in[6];
  const float* v_proj_w = (const float*)d_in[7];
  const float* idx_c_w  = (const float*)d_in[8];
  const float* idx_c_wz = (const float*)d_in[9];
  const float* idx_c_bias = (const float*)d_in[10];
  const float* w_dq     = (const float*)d_in[11];
  const float* w_iuq    = (const float*)d_in[12];
  const float* w_w      = (const float*)d_in[13];
  const float* q_norm_w = (const float*)d_in[14];
  const float* k_norm_w = (const float*)d_in[15];
  const float* group_w  = (const float*)d_in[16];
  const float* final_w  = (const float*)d_in[17];
  float* out = (float*)d_out;

  float* ws = (float*)d_ws;
  size_t off = 0;
  auto alloc = [&](size_t nfloats) { float* p = ws + off; off += nfloats; return p; };
  float* cosT  = alloc((size_t)T_LEN * 32);
  float* sinT  = alloc((size_t)T_LEN * 32);
  u16* qb      = (u16*)alloc((size_t)T_LEN * 1024);
  u16* attnb   = (u16*)alloc((size_t)T_LEN * 1024);
  u16* hb      = (u16*)alloc((size_t)T_LEN * 1024);
  float* kvout = alloc((size_t)T_LEN * 512);
  float* ibuf  = alloc((size_t)T_LEN * 228);
  float* kT    = alloc((size_t)64 * NBLK);
  float* ckv   = alloc((size_t)NBLK * 128);
  float* qib   = alloc((size_t)T_LEN * 256);
  int*   topi  = (int*)alloc((size_t)T_LEN * 64);
  u16* w_qcT   = (u16*)alloc((size_t)512 * 1024);     // rows 0-511 of fused B
  u16* kvT     = (u16*)alloc((size_t)512 * 1024);     // rows 512-1023 (contiguous!)
  u16* w_qupT  = (u16*)alloc((size_t)2048 * 256);
  u16* gwT     = (u16*)alloc((size_t)4 * 512 * 256);
  u16* fwT     = (u16*)alloc((size_t)2048 * 1024);
  float* part  = alloc((size_t)4 * T_LEN * NIDX);     // split-K partials
  float* Bcat  = (float*)attnb;                       // 2048 x 196 f32
  u16* hq1b    = (u16*)((float*)attnb + 524288);
  u16* og      = qb;

  rope_cs_k<<<(T_LEN * 32 + 255) / 256, 256, 0, stream>>>(cosT, sinT);
  castk<<<(T_LEN * 2048 / 4 + 255) / 256, 256, 0, stream>>>(h, hb, T_LEN * 2048 / 4);
  tcast_k<<<dim3(16, 64), 256, 0, stream>>>(w_qc, w_qcT, 2048, 512);
  tcast_k<<<dim3(4, 64), 256, 0, stream>>>(k_proj_w, kvT + (size_t)0 * 128 * 2048, 2048, 128);
  tcast_k<<<dim3(4, 64), 256, 0, stream>>>(v_proj_w, kvT + (size_t)1 * 128 * 2048, 2048, 128);
  tcast_k<<<dim3(4, 64), 256, 0, stream>>>(kvc_w,    kvT + (size_t)2 * 128 * 2048, 2048, 128);
  tcast_k<<<dim3(4, 64), 256, 0, stream>>>(kvc_wz,   kvT + (size_t)3 * 128 * 2048, 2048, 128);
  tcast_k<<<dim3(64, 16), 256, 0, stream>>>(w_qup, w_qupT, 512, 2048);
  for (int g = 0; g < 4; ++g)
    tcast_k<<<dim3(16, 16), 256, 0, stream>>>(group_w + (size_t)g * 512 * 512,
                                              gwT + (size_t)g * 512 * 512, 512, 512);
  tcast_k<<<dim3(64, 64), 256, 0, stream>>>(final_w, fwT, 2048, 2048);
  concat_idx_k<<<(2048 * NIDX + 255) / 256, 256, 0, stream>>>(idx_c_w, idx_c_wz, w_dq, w_w, Bcat);

  // fused qc + k|v|kvc projections (one N=1024 bf16 MFMA GEMM, split outputs)
  bgemm_qckv_k<<<dim3(8, 64), 256, 0, stream>>>(hb, w_qcT, hq1b, kvout);

  // q chain tail
  bgemm_k<1><<<dim3(16, 64), 256, 0, stream>>>(hq1b, 512, w_qupT, 512, qb, 2048, 512);
  q_rope_norm_k<<<T_LEN * 4, 256, 0, stream>>>(qb, cosT, sinT, q_norm_w);

  // sliding-window k norm/rope + kv compression (normalize f32 rows in place)
  k_norm_rope_k<<<T_LEN / 4, 256, 0, stream>>>(kvout, cosT, sinT, k_norm_w);
  compress_k<<<(NBLK * 128 + 255) / 256, 256, 0, stream>>>(
      kvout + 256, kvout + 384, 512, kvc_bias, ckv, 128, 128, 1);
  rms_rows_k<<<NBLK / 4, 256, 0, stream>>>(ckv, k_norm_w);

  // index path (f32 exact for selection stability; split-K for occupancy)
  sgemm_splitk_k<<<dim3(4, 128, 4), 256, 0, stream>>>(h, HID, Bcat, NIDX, part, NIDX, T_LEN, NIDX, 512);
  reduce4_k<<<(T_LEN * NIDX + 255) / 256, 256, 0, stream>>>(part, NIDX, ibuf, 228, T_LEN);
  compress_k<<<(NBLK * 64 + 255) / 256, 256, 0, stream>>>(
      ibuf, ibuf + 64, 228, idx_c_bias, kT, 64, 1, NBLK);
  sgemm_k<<<dim3(4, 128), 256, 0, stream>>>(ibuf + 128, 228, w_iuq, 256, qib, 256, T_LEN, 256, 64);
  topk_k<<<T_LEN / 4, 256, 0, stream>>>(qib, ibuf + 192, 228, kT, topi);

  // attention
  sparse_attn_k<<<T_LEN, 256, 0, stream>>>(qb, ckv, topi, attnb);
  win_attn_mfma_k<<<dim3(T_LEN / 64, 16), 256, 0, stream>>>(qb, kvout, attnb);

  // output projections (bf16 MFMA): fused group projection, then final
  bgemm_group_k<<<dim3(4, 64, 4), 256, 0, stream>>>(attnb, gwT, og);
  bgemm_k<0><<<dim3(16, 64), 256, 0, stream>>>(og, 2048, fwT, 2048, out, 2048, 2048);
}